// Round 1
// baseline (3157.296 us; speedup 1.0000x reference)
//
#include <hip/hip_runtime.h>
#include <hip/hip_bf16.h>
#include <math.h>

#define N_NODES 10000
#define N_EDGES 160000
#define N_GRAPHS 64
#define F_IN    128
#define C1_DIM  128
#define C2_DIM  256
#define C3_DIM  512
#define K_CHEB  5
#define NCLS    10

// ---------- helpers ----------
static __device__ __forceinline__ unsigned flip_f(float f) {
    unsigned u = __float_as_uint(f);
    return (u & 0x80000000u) ? ~u : (u | 0x80000000u);
}
static __device__ __forceinline__ float unflip_f(unsigned u) {
    unsigned b = (u & 0x80000000u) ? (u & 0x7FFFFFFFu) : ~u;
    return __uint_as_float(b);
}

// ---------- degree / normalization ----------
__global__ void deg_kernel(const int* __restrict__ src, const int* __restrict__ dst,
                           float* __restrict__ deg_s, float* __restrict__ deg_d, int E) {
    int e = blockIdx.x * blockDim.x + threadIdx.x;
    if (e >= E) return;
    atomicAdd(&deg_s[src[e]], 1.0f);
    atomicAdd(&deg_d[dst[e]], 1.0f);
}

__global__ void dinv_kernel(const float* __restrict__ deg_s, const float* __restrict__ deg_d,
                            float* __restrict__ dinv_c, float* __restrict__ dinv_g, int n) {
    int i = blockIdx.x * blockDim.x + threadIdx.x;
    if (i >= n) return;
    float ds = deg_s[i];
    dinv_c[i] = (ds > 0.0f) ? rsqrtf(ds) : 0.0f;
    dinv_g[i] = rsqrtf(deg_d[i] + 1.0f);   // GCN adds self-loop -> deg >= 1
}

__global__ void edgew_kernel(const int* __restrict__ src, const int* __restrict__ dst,
                             const float* __restrict__ dinv_c, const float* __restrict__ dinv_g,
                             float* __restrict__ wch, float* __restrict__ nrm, int E) {
    int e = blockIdx.x * blockDim.x + threadIdx.x;
    if (e >= E) return;
    int s = src[e], d = dst[e];
    wch[e] = -(dinv_c[s] * dinv_c[d]);
    nrm[e] = dinv_g[s] * dinv_g[d];
}

// ---------- edge scatter-add: out[dst] += scale*w[e]*h[src], C = 4<<shift feats ----------
__global__ void scatter_add(const float* __restrict__ h, const int* __restrict__ src,
                            const int* __restrict__ dst, const float* __restrict__ w,
                            float scale, float* __restrict__ out, int E, int shift, int C) {
    int tid = blockIdx.x * blockDim.x + threadIdx.x;
    int e = tid >> shift;
    if (e >= E) return;
    int q = tid & ((1 << shift) - 1);
    float wt = w[e] * scale;
    int s = src[e], d = dst[e];
    const float4 v = *(const float4*)(h + (size_t)s * C + q * 4);
    float* o = out + (size_t)d * C + q * 4;
    atomicAdd(o + 0, wt * v.x);
    atomicAdd(o + 1, wt * v.y);
    atomicAdd(o + 2, wt * v.z);
    atomicAdd(o + 3, wt * v.w);
}

// ---------- elementwise ----------
__global__ void initneg_kernel(float4* __restrict__ out, const float4* __restrict__ in, int total4) {
    int i = blockIdx.x * blockDim.x + threadIdx.x;
    if (i >= total4) return;
    float4 v = in[i];
    out[i] = make_float4(-v.x, -v.y, -v.z, -v.w);
}

__global__ void relu_kernel(float4* __restrict__ p, int total4) {
    int i = blockIdx.x * blockDim.x + threadIdx.x;
    if (i >= total4) return;
    float4 v = p[i];
    v.x = fmaxf(v.x, 0.0f); v.y = fmaxf(v.y, 0.0f);
    v.z = fmaxf(v.z, 0.0f); v.w = fmaxf(v.w, 0.0f);
    p[i] = v;
}

// h[n][c] = dinv[n]^2 * t[n][c] + bias[c]   (GCN self-loop term + bias)
__global__ void gcn_init_kernel(float* __restrict__ h, const float* __restrict__ t,
                                const float* __restrict__ dinv, const float* __restrict__ bias,
                                int C, int shift, int total) {
    int tid = blockIdx.x * blockDim.x + threadIdx.x;
    if (tid >= total) return;
    int n = tid >> shift;
    int q = tid & ((1 << shift) - 1);
    float sn = dinv[n] * dinv[n];
    float4 v = *(const float4*)(t + (size_t)n * C + q * 4);
    float4 b = *(const float4*)(bias + q * 4);
    float4 r = make_float4(sn * v.x + b.x, sn * v.y + b.y, sn * v.z + b.z, sn * v.w + b.w);
    *(float4*)(h + (size_t)n * C + q * 4) = r;
}

// ---------- fp32 tiled GEMM: C[M,Nc] = (beta?C:0) + A[M,K]@B[K,Nc] (+bias) (+relu) ----------
#define BM 64
#define BN 64
#define BK 16
__global__ __launch_bounds__(256) void gemm_f32(const float* __restrict__ A,
        const float* __restrict__ B, float* __restrict__ C,
        const float* __restrict__ bias, int M, int K, int Nc, int beta, int relu) {
    __shared__ float As[BK][BM + 4];
    __shared__ float Bs[BK][BN];
    int t = threadIdx.x;
    int m0 = blockIdx.y * BM, n0 = blockIdx.x * BN;
    int tn = t & 15, tm = t >> 4;     // 16x16 threads, each 4x4 microtile
    float acc[4][4];
    #pragma unroll
    for (int i = 0; i < 4; i++)
        #pragma unroll
        for (int j = 0; j < 4; j++) acc[i][j] = 0.0f;

    for (int k0 = 0; k0 < K; k0 += BK) {
        // A tile: 64 rows x 16 k, float4 along K, transposed store into As[k][m]
        {
            int m = t >> 2;              // 0..63
            int kk = (t & 3) * 4;        // 0,4,8,12
            int gm = m0 + m;
            float4 v = make_float4(0, 0, 0, 0);
            if (gm < M) v = *(const float4*)(A + (size_t)gm * K + k0 + kk);
            As[kk + 0][m] = v.x; As[kk + 1][m] = v.y;
            As[kk + 2][m] = v.z; As[kk + 3][m] = v.w;
        }
        // B tile: 16 k x 64 cols, float4 along N
        {
            int kk = t >> 4;             // 0..15
            int n  = (t & 15) * 4;       // 0..60
            float4 v = *(const float4*)(B + (size_t)(k0 + kk) * Nc + n0 + n);
            *(float4*)&Bs[kk][n] = v;
        }
        __syncthreads();
        #pragma unroll
        for (int k = 0; k < BK; k++) {
            float4 a4 = *(const float4*)&As[k][tm * 4];
            float4 b4 = *(const float4*)&Bs[k][tn * 4];
            float a[4] = {a4.x, a4.y, a4.z, a4.w};
            float b[4] = {b4.x, b4.y, b4.z, b4.w};
            #pragma unroll
            for (int i = 0; i < 4; i++)
                #pragma unroll
                for (int j = 0; j < 4; j++) acc[i][j] += a[i] * b[j];
        }
        __syncthreads();
    }
    float4 bb = make_float4(0, 0, 0, 0);
    if (bias) bb = *(const float4*)(bias + n0 + tn * 4);
    #pragma unroll
    for (int i = 0; i < 4; i++) {
        int gm = m0 + tm * 4 + i;
        if (gm >= M) continue;
        float* cp = C + (size_t)gm * Nc + n0 + tn * 4;
        float4 c = make_float4(acc[i][0] + bb.x, acc[i][1] + bb.y,
                               acc[i][2] + bb.z, acc[i][3] + bb.w);
        if (beta) {
            float4 old = *(const float4*)cp;
            c.x += old.x; c.y += old.y; c.z += old.z; c.w += old.w;
        }
        if (relu) {
            c.x = fmaxf(c.x, 0.0f); c.y = fmaxf(c.y, 0.0f);
            c.z = fmaxf(c.z, 0.0f); c.w = fmaxf(c.w, 0.0f);
        }
        *(float4*)cp = c;
    }
}

// ---------- attention pooling ----------
__global__ void gate_kernel(const float* __restrict__ h3, const float* __restrict__ wg,
                            const float* __restrict__ bg, float* __restrict__ logits, int n) {
    int node = blockIdx.x * 4 + (threadIdx.x >> 6);
    int lane = threadIdx.x & 63;
    if (node >= n) return;
    float s = 0.0f;
    #pragma unroll
    for (int i = 0; i < 8; i++) {
        int c = i * 64 + lane;
        s += h3[(size_t)node * C3_DIM + c] * wg[c];
    }
    #pragma unroll
    for (int off = 32; off > 0; off >>= 1) s += __shfl_down(s, off);
    if (lane == 0) logits[node] = s + bg[0];
}

__global__ void amax_kernel(const float* __restrict__ logits, const int* __restrict__ batch,
                            unsigned* __restrict__ mkeys, int n) {
    int i = blockIdx.x * blockDim.x + threadIdx.x;
    if (i >= n) return;
    atomicMax(&mkeys[batch[i]], flip_f(logits[i]));
}

__global__ void expsum_kernel(float* __restrict__ logits, const int* __restrict__ batch,
                              const unsigned* __restrict__ mkeys, float* __restrict__ ssum, int n) {
    int i = blockIdx.x * blockDim.x + threadIdx.x;
    if (i >= n) return;
    int g = batch[i];
    float e = expf(logits[i] - unflip_f(mkeys[g]));
    logits[i] = e;
    atomicAdd(&ssum[g], e);
}

__global__ void pool_kernel(const float* __restrict__ h3, const float* __restrict__ enum_,
                            const float* __restrict__ ssum, const int* __restrict__ batch,
                            float* __restrict__ pooled, int n) {
    int tid = blockIdx.x * blockDim.x + threadIdx.x;
    int node = tid >> 7;              // C3/4 = 128 groups
    if (node >= n) return;
    int q = tid & 127;
    int g = batch[node];
    float alpha = enum_[node] / ssum[g];
    float4 v = *(const float4*)(h3 + (size_t)node * C3_DIM + q * 4);
    float* o = pooled + (size_t)g * C3_DIM + q * 4;
    atomicAdd(o + 0, alpha * v.x);
    atomicAdd(o + 1, alpha * v.y);
    atomicAdd(o + 2, alpha * v.z);
    atomicAdd(o + 3, alpha * v.w);
}

__global__ void fc_kernel(const float* __restrict__ pooled, const float* __restrict__ Wfc,
                          const float* __restrict__ bfc, float* __restrict__ out) {
    int g = blockIdx.x;
    int t = threadIdx.x;
    float acc = -INFINITY;
    if (t < NCLS) {
        acc = bfc[t];
        for (int k = 0; k < C3_DIM; k++)
            acc += pooled[(size_t)g * C3_DIM + k] * Wfc[k * NCLS + t];
    }
    float m = acc;
    #pragma unroll
    for (int off = 8; off > 0; off >>= 1) m = fmaxf(m, __shfl_xor(m, off, 16));
    float e = (t < NCLS) ? expf(acc - m) : 0.0f;
    float s = e;
    #pragma unroll
    for (int off = 8; off > 0; off >>= 1) s += __shfl_xor(s, off, 16);
    if (t < NCLS) out[g * NCLS + t] = acc - m - logf(s);
}

// ---------- host ----------
extern "C" void kernel_launch(void* const* d_in, const int* in_sizes, int n_in,
                              void* d_out, int out_size, void* d_ws, size_t ws_size,
                              hipStream_t stream) {
    const float* x      = (const float*)d_in[0];
    const int*   ei     = (const int*)d_in[1];
    const int*   batch  = (const int*)d_in[2];
    const float* W_cheb = (const float*)d_in[3];
    const float* b_cheb = (const float*)d_in[4];
    const float* W_g1   = (const float*)d_in[5];
    const float* b_g1   = (const float*)d_in[6];
    const float* W_g2   = (const float*)d_in[7];
    const float* b_g2   = (const float*)d_in[8];
    const float* w_gate = (const float*)d_in[9];
    const float* b_gate = (const float*)d_in[10];
    const float* W_fc   = (const float*)d_in[11];
    const float* b_fc   = (const float*)d_in[12];
    const int* src = ei;
    const int* dst = ei + N_EDGES;
    float* out = (float*)d_out;

    const int N = N_NODES, E = N_EDGES, G = N_GRAPHS;
    const int NF = N * F_IN;

    float* W = (float*)d_ws;
    float* deg_s  = W; W += N;
    float* deg_d  = W; W += N;
    float* dinv_c = W; W += N;
    float* dinv_g = W; W += N;
    float* wch    = W; W += E;
    float* nrm    = W; W += E;
    float* txA    = W; W += NF;
    float* txB    = W; W += NF;
    float* txC    = W; W += NF;
    float* h1     = W; W += (size_t)N * C1_DIM;
    float* t2     = W; W += (size_t)N * C2_DIM;
    float* h2     = W; W += (size_t)N * C2_DIM;
    float* t3     = W; W += (size_t)N * C3_DIM;
    float* h3     = W; W += (size_t)N * C3_DIM;
    float* logits = W; W += N;
    float* mkeys  = W; W += G;   // used as unsigned
    float* ssum   = W; W += G;
    float* pooled = W; W += (size_t)G * C3_DIM;

    dim3 blk(256);
    auto cdiv = [](int a, int b) { return (a + b - 1) / b; };

    auto gemm = [&](const float* A, const float* B, float* Co, const float* bias,
                    int M, int K, int Nc, int beta, int relu) {
        dim3 grid(Nc / BN, cdiv(M, BM));
        hipLaunchKernelGGL(gemm_f32, grid, dim3(256), 0, stream, A, B, Co, bias, M, K, Nc, beta, relu);
    };

    // --- degrees & edge weights ---
    hipMemsetAsync(deg_s, 0, 2 * N * sizeof(float), stream);
    hipLaunchKernelGGL(deg_kernel, dim3(cdiv(E, 256)), blk, 0, stream, src, dst, deg_s, deg_d, E);
    hipLaunchKernelGGL(dinv_kernel, dim3(cdiv(N, 256)), blk, 0, stream, deg_s, deg_d, dinv_c, dinv_g, N);
    hipLaunchKernelGGL(edgew_kernel, dim3(cdiv(E, 256)), blk, 0, stream, src, dst, dinv_c, dinv_g, wch, nrm, E);

    // --- ChebConv: h1 = sum_k T_k @ W[k] + b, relu ---
    const int WC = F_IN * C1_DIM;
    gemm(x, W_cheb + 0 * WC, h1, b_cheb, N, F_IN, C1_DIM, 0, 0);          // T0 = x

    hipMemsetAsync(txA, 0, (size_t)NF * sizeof(float), stream);           // T1 = prop(x)
    hipLaunchKernelGGL(scatter_add, dim3(cdiv(E * 32, 256)), blk, 0, stream,
                       x, src, dst, wch, 1.0f, txA, E, 5, F_IN);
    gemm(txA, W_cheb + 1 * WC, h1, nullptr, N, F_IN, C1_DIM, 1, 0);

    hipLaunchKernelGGL(initneg_kernel, dim3(cdiv(NF / 4, 256)), blk, 0, stream,  // T2 = 2*prop(T1) - T0
                       (float4*)txB, (const float4*)x, NF / 4);
    hipLaunchKernelGGL(scatter_add, dim3(cdiv(E * 32, 256)), blk, 0, stream,
                       txA, src, dst, wch, 2.0f, txB, E, 5, F_IN);
    gemm(txB, W_cheb + 2 * WC, h1, nullptr, N, F_IN, C1_DIM, 1, 0);

    hipLaunchKernelGGL(initneg_kernel, dim3(cdiv(NF / 4, 256)), blk, 0, stream,  // T3
                       (float4*)txC, (const float4*)txA, NF / 4);
    hipLaunchKernelGGL(scatter_add, dim3(cdiv(E * 32, 256)), blk, 0, stream,
                       txB, src, dst, wch, 2.0f, txC, E, 5, F_IN);
    gemm(txC, W_cheb + 3 * WC, h1, nullptr, N, F_IN, C1_DIM, 1, 0);

    hipLaunchKernelGGL(initneg_kernel, dim3(cdiv(NF / 4, 256)), blk, 0, stream,  // T4 (reuse txA)
                       (float4*)txA, (const float4*)txB, NF / 4);
    hipLaunchKernelGGL(scatter_add, dim3(cdiv(E * 32, 256)), blk, 0, stream,
                       txC, src, dst, wch, 2.0f, txA, E, 5, F_IN);
    gemm(txA, W_cheb + 4 * WC, h1, nullptr, N, F_IN, C1_DIM, 1, 1);       // + relu

    // --- GCN1: h2 = relu(agg(norm * (h1@W_g1)) + selfloop + b) ---
    gemm(h1, W_g1, t2, nullptr, N, C1_DIM, C2_DIM, 0, 0);
    hipLaunchKernelGGL(gcn_init_kernel, dim3(cdiv(N * (C2_DIM / 4), 256)), blk, 0, stream,
                       h2, t2, dinv_g, b_g1, C2_DIM, 6, N * (C2_DIM / 4));
    hipLaunchKernelGGL(scatter_add, dim3(cdiv(E * 64, 256)), blk, 0, stream,
                       t2, src, dst, nrm, 1.0f, h2, E, 6, C2_DIM);
    hipLaunchKernelGGL(relu_kernel, dim3(cdiv(N * C2_DIM / 4, 256)), blk, 0, stream,
                       (float4*)h2, N * C2_DIM / 4);

    // --- GCN2: h3 ---
    gemm(h2, W_g2, t3, nullptr, N, C2_DIM, C3_DIM, 0, 0);
    hipLaunchKernelGGL(gcn_init_kernel, dim3(cdiv(N * (C3_DIM / 4), 256)), blk, 0, stream,
                       h3, t3, dinv_g, b_g2, C3_DIM, 7, N * (C3_DIM / 4));
    hipLaunchKernelGGL(scatter_add, dim3(cdiv(E * 128, 256)), blk, 0, stream,
                       t3, src, dst, nrm, 1.0f, h3, E, 7, C3_DIM);
    hipLaunchKernelGGL(relu_kernel, dim3(cdiv(N * C3_DIM / 4, 256)), blk, 0, stream,
                       (float4*)h3, N * C3_DIM / 4);

    // --- attention pool ---
    hipLaunchKernelGGL(gate_kernel, dim3(cdiv(N, 4)), blk, 0, stream, h3, w_gate, b_gate, logits, N);
    hipMemsetAsync(mkeys, 0, 2 * G * sizeof(float), stream);   // mkeys + ssum
    hipLaunchKernelGGL(amax_kernel, dim3(cdiv(N, 256)), blk, 0, stream,
                       logits, batch, (unsigned*)mkeys, N);
    hipLaunchKernelGGL(expsum_kernel, dim3(cdiv(N, 256)), blk, 0, stream,
                       logits, batch, (const unsigned*)mkeys, ssum, N);
    hipMemsetAsync(pooled, 0, (size_t)G * C3_DIM * sizeof(float), stream);
    hipLaunchKernelGGL(pool_kernel, dim3(cdiv(N * 128, 256)), blk, 0, stream,
                       h3, logits, ssum, batch, pooled, N);

    // --- FC + log_softmax ---
    hipLaunchKernelGGL(fc_kernel, dim3(G), dim3(64), 0, stream, pooled, W_fc, b_fc, out);
}

// Round 2
// 645.171 us; speedup vs baseline: 4.8937x; 4.8937x over previous
//
#include <hip/hip_runtime.h>
#include <hip/hip_bf16.h>
#include <math.h>

#define N_NODES 10000
#define N_EDGES 160000
#define N_GRAPHS 64
#define F_IN    128
#define C1_DIM  128
#define C2_DIM  256
#define C3_DIM  512
#define K_CHEB  5
#define NCLS    10

// ---------- helpers ----------
static __device__ __forceinline__ unsigned flip_f(float f) {
    unsigned u = __float_as_uint(f);
    return (u & 0x80000000u) ? ~u : (u | 0x80000000u);
}
static __device__ __forceinline__ float unflip_f(unsigned u) {
    unsigned b = (u & 0x80000000u) ? (u & 0x7FFFFFFFu) : ~u;
    return __uint_as_float(b);
}

// ---------- CSR build ----------
__global__ void count_kernel(const int* __restrict__ src, const int* __restrict__ dst,
                             int* __restrict__ cnt_s, int* __restrict__ cnt_d, int E) {
    int e = blockIdx.x * blockDim.x + threadIdx.x;
    if (e >= E) return;
    atomicAdd(&cnt_s[src[e]], 1);
    atomicAdd(&cnt_d[dst[e]], 1);
}

__global__ void dinv_kernel(const int* __restrict__ cnt_s, const int* __restrict__ cnt_d,
                            float* __restrict__ dinv_c, float* __restrict__ dinv_g, int n) {
    int i = blockIdx.x * blockDim.x + threadIdx.x;
    if (i >= n) return;
    int cs = cnt_s[i];
    dinv_c[i] = (cs > 0) ? rsqrtf((float)cs) : 0.0f;
    dinv_g[i] = rsqrtf((float)cnt_d[i] + 1.0f);   // GCN self-loop -> deg >= 1
}

// single-block exclusive scan over n (<= a few 10k) -> rowptr[0..n]
__global__ void scan_kernel(const int* __restrict__ cnt, int* __restrict__ rowptr, int n) {
    __shared__ int tmp[256];
    __shared__ int carry_s;
    int tid = threadIdx.x;
    if (tid == 0) carry_s = 0;
    __syncthreads();
    for (int base = 0; base < n; base += 256) {
        int i = base + tid;
        int v = (i < n) ? cnt[i] : 0;
        tmp[tid] = v;
        __syncthreads();
        for (int off = 1; off < 256; off <<= 1) {
            int t = (tid >= off) ? tmp[tid - off] : 0;
            __syncthreads();
            tmp[tid] += t;
            __syncthreads();
        }
        int incl = tmp[tid];
        int carry = carry_s;
        if (i < n) rowptr[i] = carry + incl - v;   // exclusive
        __syncthreads();
        if (tid == 255) carry_s = carry + incl;
        __syncthreads();
    }
    if (tid == 0) rowptr[n] = carry_s;
}

__global__ void fill_kernel(const int* __restrict__ src, const int* __restrict__ dst,
                            const float* __restrict__ dinv_c, const float* __restrict__ dinv_g,
                            const int* __restrict__ rowptr, int* __restrict__ fillc,
                            int* __restrict__ col, float* __restrict__ wch,
                            float* __restrict__ nrm, int E) {
    int e = blockIdx.x * blockDim.x + threadIdx.x;
    if (e >= E) return;
    int s = src[e], d = dst[e];
    int pos = rowptr[d] + atomicAdd(&fillc[d], 1);
    col[pos] = s;
    wch[pos] = -(dinv_c[s] * dinv_c[d]);
    nrm[pos] = dinv_g[s] * dinv_g[d];
}

// ---------- CSR gather: one wave per dst node, lanes over features ----------
// cheb: out[n][c] = alpha * sum_e w[e]*h[col[e]][c] + beta * base[n][c]
template<int FPL>   // floats per lane; C = FPL*64
__global__ __launch_bounds__(256) void gather_cheb(
        const float* __restrict__ h, const int* __restrict__ rowptr,
        const int* __restrict__ col, const float* __restrict__ ew,
        const float* __restrict__ base, float alpha, float beta,
        float* __restrict__ out, int n) {
    const int C = FPL * 64;
    int w = (blockIdx.x * blockDim.x + threadIdx.x) >> 6;
    int lane = threadIdx.x & 63;
    if (w >= n) return;
    float acc[FPL];
    #pragma unroll
    for (int q = 0; q < FPL; q++) acc[q] = 0.0f;
    int rs = rowptr[w], re = rowptr[w + 1];
    for (int b = rs; b < re; b += 64) {
        int cl = 0; float wl = 0.0f;
        if (b + lane < re) { cl = col[b + lane]; wl = ew[b + lane]; }
        int nk = min(64, re - b);
        for (int j = 0; j < nk; j++) {
            int s = __shfl(cl, j);
            float we = __shfl(wl, j);
            const float* hp = h + (size_t)s * C + lane * FPL;
            if constexpr (FPL == 2) {
                float2 v = *(const float2*)hp;
                acc[0] += we * v.x; acc[1] += we * v.y;
            } else {
                #pragma unroll
                for (int q = 0; q < FPL; q += 4) {
                    float4 v = *(const float4*)(hp + q);
                    acc[q+0] += we * v.x; acc[q+1] += we * v.y;
                    acc[q+2] += we * v.z; acc[q+3] += we * v.w;
                }
            }
        }
    }
    float* op = out + (size_t)w * C + lane * FPL;
    if (base) {
        const float* bp = base + (size_t)w * C + lane * FPL;
        #pragma unroll
        for (int q = 0; q < FPL; q++) op[q] = alpha * acc[q] + beta * bp[q];
    } else {
        #pragma unroll
        for (int q = 0; q < FPL; q++) op[q] = alpha * acc[q];
    }
}

// gcn: out[n][c] = relu( sum_e nrm[e]*t[col[e]][c] + dinv[n]^2 * t[n][c] + bias[c] )
template<int FPL>
__global__ __launch_bounds__(256) void gather_gcn(
        const float* __restrict__ t, const int* __restrict__ rowptr,
        const int* __restrict__ col, const float* __restrict__ ew,
        const float* __restrict__ dinv, const float* __restrict__ bias,
        float* __restrict__ out, int n) {
    const int C = FPL * 64;
    int w = (blockIdx.x * blockDim.x + threadIdx.x) >> 6;
    int lane = threadIdx.x & 63;
    if (w >= n) return;
    float acc[FPL];
    #pragma unroll
    for (int q = 0; q < FPL; q++) acc[q] = 0.0f;
    int rs = rowptr[w], re = rowptr[w + 1];
    for (int b = rs; b < re; b += 64) {
        int cl = 0; float wl = 0.0f;
        if (b + lane < re) { cl = col[b + lane]; wl = ew[b + lane]; }
        int nk = min(64, re - b);
        for (int j = 0; j < nk; j++) {
            int s = __shfl(cl, j);
            float we = __shfl(wl, j);
            const float* tp = t + (size_t)s * C + lane * FPL;
            #pragma unroll
            for (int q = 0; q < FPL; q += 4) {
                float4 v = *(const float4*)(tp + q);
                acc[q+0] += we * v.x; acc[q+1] += we * v.y;
                acc[q+2] += we * v.z; acc[q+3] += we * v.w;
            }
        }
    }
    float sn = dinv[w] * dinv[w];
    const float* selfp = t + (size_t)w * C + lane * FPL;
    const float* bp = bias + lane * FPL;
    float* op = out + (size_t)w * C + lane * FPL;
    #pragma unroll
    for (int q = 0; q < FPL; q++)
        op[q] = fmaxf(acc[q] + sn * selfp[q] + bp[q], 0.0f);
}

// ---------- fp32 tiled GEMM: C[M,Nc] = (beta?C:0) + A[M,K]@B[K,Nc] (+bias) (+relu) ----------
#define BM 64
#define BN 64
#define BK 16
__global__ __launch_bounds__(256) void gemm_f32(const float* __restrict__ A,
        const float* __restrict__ B, float* __restrict__ C,
        const float* __restrict__ bias, int M, int K, int Nc, int beta, int relu) {
    __shared__ float As[BK][BM + 4];
    __shared__ float Bs[BK][BN];
    int t = threadIdx.x;
    int m0 = blockIdx.y * BM, n0 = blockIdx.x * BN;
    int tn = t & 15, tm = t >> 4;     // 16x16 threads, each 4x4 microtile
    float acc[4][4];
    #pragma unroll
    for (int i = 0; i < 4; i++)
        #pragma unroll
        for (int j = 0; j < 4; j++) acc[i][j] = 0.0f;

    for (int k0 = 0; k0 < K; k0 += BK) {
        {
            int m = t >> 2;
            int kk = (t & 3) * 4;
            int gm = m0 + m;
            float4 v = make_float4(0, 0, 0, 0);
            if (gm < M) v = *(const float4*)(A + (size_t)gm * K + k0 + kk);
            As[kk + 0][m] = v.x; As[kk + 1][m] = v.y;
            As[kk + 2][m] = v.z; As[kk + 3][m] = v.w;
        }
        {
            int kk = t >> 4;
            int n  = (t & 15) * 4;
            float4 v = *(const float4*)(B + (size_t)(k0 + kk) * Nc + n0 + n);
            *(float4*)&Bs[kk][n] = v;
        }
        __syncthreads();
        #pragma unroll
        for (int k = 0; k < BK; k++) {
            float4 a4 = *(const float4*)&As[k][tm * 4];
            float4 b4 = *(const float4*)&Bs[k][tn * 4];
            float a[4] = {a4.x, a4.y, a4.z, a4.w};
            float b[4] = {b4.x, b4.y, b4.z, b4.w};
            #pragma unroll
            for (int i = 0; i < 4; i++)
                #pragma unroll
                for (int j = 0; j < 4; j++) acc[i][j] += a[i] * b[j];
        }
        __syncthreads();
    }
    float4 bb = make_float4(0, 0, 0, 0);
    if (bias) bb = *(const float4*)(bias + n0 + tn * 4);
    #pragma unroll
    for (int i = 0; i < 4; i++) {
        int gm = m0 + tm * 4 + i;
        if (gm >= M) continue;
        float* cp = C + (size_t)gm * Nc + n0 + tn * 4;
        float4 c = make_float4(acc[i][0] + bb.x, acc[i][1] + bb.y,
                               acc[i][2] + bb.z, acc[i][3] + bb.w);
        if (beta) {
            float4 old = *(const float4*)cp;
            c.x += old.x; c.y += old.y; c.z += old.z; c.w += old.w;
        }
        if (relu) {
            c.x = fmaxf(c.x, 0.0f); c.y = fmaxf(c.y, 0.0f);
            c.z = fmaxf(c.z, 0.0f); c.w = fmaxf(c.w, 0.0f);
        }
        *(float4*)cp = c;
    }
}

// ---------- attention pooling ----------
__global__ void gate_kernel(const float* __restrict__ h3, const float* __restrict__ wg,
                            const float* __restrict__ bg, float* __restrict__ logits, int n) {
    int node = blockIdx.x * 4 + (threadIdx.x >> 6);
    int lane = threadIdx.x & 63;
    if (node >= n) return;
    float s = 0.0f;
    #pragma unroll
    for (int i = 0; i < 8; i++) {
        int c = i * 64 + lane;
        s += h3[(size_t)node * C3_DIM + c] * wg[c];
    }
    #pragma unroll
    for (int off = 32; off > 0; off >>= 1) s += __shfl_down(s, off);
    if (lane == 0) logits[node] = s + bg[0];
}

__global__ void amax_kernel(const float* __restrict__ logits, const int* __restrict__ batch,
                            unsigned* __restrict__ mkeys, int n) {
    int i = blockIdx.x * blockDim.x + threadIdx.x;
    if (i >= n) return;
    atomicMax(&mkeys[batch[i]], flip_f(logits[i]));
}

__global__ void expsum_kernel(float* __restrict__ logits, const int* __restrict__ batch,
                              const unsigned* __restrict__ mkeys, float* __restrict__ ssum, int n) {
    int i = blockIdx.x * blockDim.x + threadIdx.x;
    if (i >= n) return;
    int g = batch[i];
    float e = expf(logits[i] - unflip_f(mkeys[g]));
    logits[i] = e;
    atomicAdd(&ssum[g], e);
}

__global__ void pool_kernel(const float* __restrict__ h3, const float* __restrict__ enum_,
                            const float* __restrict__ ssum, const int* __restrict__ batch,
                            float* __restrict__ pooled, int n) {
    int tid = blockIdx.x * blockDim.x + threadIdx.x;
    int node = tid >> 7;              // C3/4 = 128 groups
    if (node >= n) return;
    int q = tid & 127;
    int g = batch[node];
    float alpha = enum_[node] / ssum[g];
    float4 v = *(const float4*)(h3 + (size_t)node * C3_DIM + q * 4);
    float* o = pooled + (size_t)g * C3_DIM + q * 4;
    atomicAdd(o + 0, alpha * v.x);
    atomicAdd(o + 1, alpha * v.y);
    atomicAdd(o + 2, alpha * v.z);
    atomicAdd(o + 3, alpha * v.w);
}

__global__ void fc_kernel(const float* __restrict__ pooled, const float* __restrict__ Wfc,
                          const float* __restrict__ bfc, float* __restrict__ out) {
    int g = blockIdx.x;
    int t = threadIdx.x;
    float acc = -INFINITY;
    if (t < NCLS) {
        acc = bfc[t];
        for (int k = 0; k < C3_DIM; k++)
            acc += pooled[(size_t)g * C3_DIM + k] * Wfc[k * NCLS + t];
    }
    float m = acc;
    #pragma unroll
    for (int off = 8; off > 0; off >>= 1) m = fmaxf(m, __shfl_xor(m, off, 16));
    float e = (t < NCLS) ? expf(acc - m) : 0.0f;
    float s = e;
    #pragma unroll
    for (int off = 8; off > 0; off >>= 1) s += __shfl_xor(s, off, 16);
    if (t < NCLS) out[g * NCLS + t] = acc - m - logf(s);
}

// ---------- host ----------
extern "C" void kernel_launch(void* const* d_in, const int* in_sizes, int n_in,
                              void* d_out, int out_size, void* d_ws, size_t ws_size,
                              hipStream_t stream) {
    const float* x      = (const float*)d_in[0];
    const int*   ei     = (const int*)d_in[1];
    const int*   batch  = (const int*)d_in[2];
    const float* W_cheb = (const float*)d_in[3];
    const float* b_cheb = (const float*)d_in[4];
    const float* W_g1   = (const float*)d_in[5];
    const float* b_g1   = (const float*)d_in[6];
    const float* W_g2   = (const float*)d_in[7];
    const float* b_g2   = (const float*)d_in[8];
    const float* w_gate = (const float*)d_in[9];
    const float* b_gate = (const float*)d_in[10];
    const float* W_fc   = (const float*)d_in[11];
    const float* b_fc   = (const float*)d_in[12];
    const int* src = ei;
    const int* dst = ei + N_EDGES;
    float* out = (float*)d_out;

    const int N = N_NODES, E = N_EDGES, G = N_GRAPHS;
    const int NF = N * F_IN;

    char* W = (char*)d_ws;
    auto alloc = [&](size_t elems) { void* p = W; W += elems * 4; return p; };
    int*   cnt_s   = (int*)alloc(N);
    int*   cnt_d   = (int*)alloc(N);
    int*   fillc   = (int*)alloc(N);
    int*   rowptr  = (int*)alloc(N + 4);
    int*   col     = (int*)alloc(E);
    float* wch     = (float*)alloc(E);
    float* nrm     = (float*)alloc(E);
    float* dinv_c  = (float*)alloc(N);
    float* dinv_g  = (float*)alloc(N);
    float* txA     = (float*)alloc(NF);
    float* txB     = (float*)alloc(NF);
    float* txC     = (float*)alloc(NF);
    float* h1      = (float*)alloc((size_t)N * C1_DIM);
    float* t2      = (float*)alloc((size_t)N * C2_DIM);
    float* h2      = (float*)alloc((size_t)N * C2_DIM);
    float* t3      = (float*)alloc((size_t)N * C3_DIM);
    float* h3      = (float*)alloc((size_t)N * C3_DIM);
    float* logits  = (float*)alloc(N);
    float* mkeys   = (float*)alloc(G);
    float* ssum    = (float*)alloc(G);
    float* pooled  = (float*)alloc((size_t)G * C3_DIM);

    dim3 blk(256);
    auto cdiv = [](int a, int b) { return (a + b - 1) / b; };

    auto gemm = [&](const float* A, const float* B, float* Co, const float* bias,
                    int M, int K, int Nc, int beta, int relu) {
        dim3 grid(Nc / BN, cdiv(M, BM));
        hipLaunchKernelGGL(gemm_f32, grid, dim3(256), 0, stream, A, B, Co, bias, M, K, Nc, beta, relu);
    };

    // --- CSR build (dst-sorted), shared by cheb + gcn aggregations ---
    hipMemsetAsync(cnt_s, 0, 3 * N * sizeof(int), stream);   // cnt_s, cnt_d, fillc
    hipLaunchKernelGGL(count_kernel, dim3(cdiv(E, 256)), blk, 0, stream, src, dst, cnt_s, cnt_d, E);
    hipLaunchKernelGGL(dinv_kernel, dim3(cdiv(N, 256)), blk, 0, stream, cnt_s, cnt_d, dinv_c, dinv_g, N);
    hipLaunchKernelGGL(scan_kernel, dim3(1), blk, 0, stream, cnt_d, rowptr, N);
    hipLaunchKernelGGL(fill_kernel, dim3(cdiv(E, 256)), blk, 0, stream,
                       src, dst, dinv_c, dinv_g, rowptr, fillc, col, wch, nrm, E);

    const int NWB = cdiv(N, 4);   // gather: 4 waves/block, 1 node/wave

    // --- ChebConv: h1 = sum_k T_k @ W[k] + b, relu on last ---
    const int WC = F_IN * C1_DIM;
    gemm(x, W_cheb + 0 * WC, h1, b_cheb, N, F_IN, C1_DIM, 0, 0);            // T0 = x

    hipLaunchKernelGGL(gather_cheb<2>, dim3(NWB), blk, 0, stream,           // T1 = prop(x)
                       x, rowptr, col, wch, (const float*)nullptr, 1.0f, 0.0f, txA, N);
    gemm(txA, W_cheb + 1 * WC, h1, nullptr, N, F_IN, C1_DIM, 1, 0);

    hipLaunchKernelGGL(gather_cheb<2>, dim3(NWB), blk, 0, stream,           // T2 = 2*prop(T1) - T0
                       txA, rowptr, col, wch, x, 2.0f, -1.0f, txB, N);
    gemm(txB, W_cheb + 2 * WC, h1, nullptr, N, F_IN, C1_DIM, 1, 0);

    hipLaunchKernelGGL(gather_cheb<2>, dim3(NWB), blk, 0, stream,           // T3
                       txB, rowptr, col, wch, txA, 2.0f, -1.0f, txC, N);
    gemm(txC, W_cheb + 3 * WC, h1, nullptr, N, F_IN, C1_DIM, 1, 0);

    hipLaunchKernelGGL(gather_cheb<2>, dim3(NWB), blk, 0, stream,           // T4 (reuse txA)
                       txC, rowptr, col, wch, txB, 2.0f, -1.0f, txA, N);
    gemm(txA, W_cheb + 4 * WC, h1, nullptr, N, F_IN, C1_DIM, 1, 1);         // + relu

    // --- GCN1: h2 = relu(agg(nrm * t2[src]) + dinv^2*t2 + b) ---
    gemm(h1, W_g1, t2, nullptr, N, C1_DIM, C2_DIM, 0, 0);
    hipLaunchKernelGGL(gather_gcn<4>, dim3(NWB), blk, 0, stream,
                       t2, rowptr, col, nrm, dinv_g, b_g1, h2, N);

    // --- GCN2: h3 ---
    gemm(h2, W_g2, t3, nullptr, N, C2_DIM, C3_DIM, 0, 0);
    hipLaunchKernelGGL(gather_gcn<8>, dim3(NWB), blk, 0, stream,
                       t3, rowptr, col, nrm, dinv_g, b_g2, h3, N);

    // --- attention pool ---
    hipLaunchKernelGGL(gate_kernel, dim3(cdiv(N, 4)), blk, 0, stream, h3, w_gate, b_gate, logits, N);
    hipMemsetAsync(mkeys, 0, 2 * G * sizeof(float), stream);   // mkeys + ssum
    hipLaunchKernelGGL(amax_kernel, dim3(cdiv(N, 256)), blk, 0, stream,
                       logits, batch, (unsigned*)mkeys, N);
    hipLaunchKernelGGL(expsum_kernel, dim3(cdiv(N, 256)), blk, 0, stream,
                       logits, batch, (const unsigned*)mkeys, ssum, N);
    hipMemsetAsync(pooled, 0, (size_t)G * C3_DIM * sizeof(float), stream);
    hipLaunchKernelGGL(pool_kernel, dim3(cdiv(N * 128, 256)), blk, 0, stream,
                       h3, logits, ssum, batch, pooled, N);

    // --- FC + log_softmax ---
    hipLaunchKernelGGL(fc_kernel, dim3(G), dim3(64), 0, stream, pooled, W_fc, b_fc, out);
}

// Round 3
// 413.084 us; speedup vs baseline: 7.6432x; 1.5618x over previous
//
#include <hip/hip_runtime.h>
#include <hip/hip_bf16.h>
#include <math.h>

#define N_NODES 10000
#define N_EDGES 160000
#define N_GRAPHS 64
#define F_IN    128
#define C1_DIM  128
#define C2_DIM  256
#define C3_DIM  512
#define K_CHEB  5
#define NCLS    10

typedef short v8s __attribute__((ext_vector_type(8)));
typedef float v4f __attribute__((ext_vector_type(4)));
typedef unsigned short ushort_t;

// ---------- bf16 helpers ----------
static __device__ __forceinline__ unsigned short f2bf(float f) {
    unsigned u = __float_as_uint(f);
    unsigned r = (u + 0x7FFFu + ((u >> 16) & 1u)) >> 16;   // RNE
    return (unsigned short)r;
}
static __device__ __forceinline__ float bf_lo(unsigned u) {   // low ushort -> f32
    return __uint_as_float(u << 16);
}
static __device__ __forceinline__ float bf_hi(unsigned u) {   // high ushort -> f32
    return __uint_as_float(u & 0xFFFF0000u);
}

// ---------- CSR build ----------
__global__ void count_kernel(const int* __restrict__ src, const int* __restrict__ dst,
                             int* __restrict__ cnt_s, int* __restrict__ cnt_d, int E) {
    int e = blockIdx.x * blockDim.x + threadIdx.x;
    if (e >= E) return;
    atomicAdd(&cnt_s[src[e]], 1);
    atomicAdd(&cnt_d[dst[e]], 1);
}

__global__ void dinv_kernel(const int* __restrict__ cnt_s, const int* __restrict__ cnt_d,
                            float* __restrict__ dinv_c, float* __restrict__ dinv_g, int n) {
    int i = blockIdx.x * blockDim.x + threadIdx.x;
    if (i >= n) return;
    int cs = cnt_s[i];
    dinv_c[i] = (cs > 0) ? rsqrtf((float)cs) : 0.0f;
    dinv_g[i] = rsqrtf((float)cnt_d[i] + 1.0f);   // GCN self-loop -> deg >= 1
}

// single-block exclusive scan over n -> rowptr[0..n]
__global__ void scan_kernel(const int* __restrict__ cnt, int* __restrict__ rowptr, int n) {
    __shared__ int tmp[256];
    __shared__ int carry_s;
    int tid = threadIdx.x;
    if (tid == 0) carry_s = 0;
    __syncthreads();
    for (int base = 0; base < n; base += 256) {
        int i = base + tid;
        int v = (i < n) ? cnt[i] : 0;
        tmp[tid] = v;
        __syncthreads();
        for (int off = 1; off < 256; off <<= 1) {
            int t = (tid >= off) ? tmp[tid - off] : 0;
            __syncthreads();
            tmp[tid] += t;
            __syncthreads();
        }
        int incl = tmp[tid];
        int carry = carry_s;
        if (i < n) rowptr[i] = carry + incl - v;   // exclusive
        __syncthreads();
        if (tid == 255) carry_s = carry + incl;
        __syncthreads();
    }
    if (tid == 0) rowptr[n] = carry_s;
}

__global__ void fill_kernel(const int* __restrict__ src, const int* __restrict__ dst,
                            const float* __restrict__ dinv_c, const float* __restrict__ dinv_g,
                            const int* __restrict__ rowptr, int* __restrict__ fillc,
                            int* __restrict__ col, float* __restrict__ wch,
                            float* __restrict__ nrm, int E) {
    int e = blockIdx.x * blockDim.x + threadIdx.x;
    if (e >= E) return;
    int s = src[e], d = dst[e];
    int pos = rowptr[d] + atomicAdd(&fillc[d], 1);
    col[pos] = s;
    wch[pos] = -(dinv_c[s] * dinv_c[d]);
    nrm[pos] = dinv_g[s] * dinv_g[d];
}

// ---------- converts ----------
// x fp32 -> xb bf16 [N][128] and Tcat slice 0
__global__ void conv_x_kernel(const float* __restrict__ x, unsigned short* __restrict__ xb,
                              unsigned short* __restrict__ tcat) {
    int id = blockIdx.x * blockDim.x + threadIdx.x;
    if (id >= N_NODES * 64) return;
    int n = id >> 6, f = (id & 63) * 2;
    float2 v = *(const float2*)(x + (size_t)n * F_IN + f);
    ushort2 o; o.x = f2bf(v.x); o.y = f2bf(v.y);
    *(ushort2*)(xb + (size_t)n * F_IN + f) = o;
    *(ushort2*)(tcat + (size_t)n * (K_CHEB * F_IN) + f) = o;
}

// W [K,N] fp32 row-major -> Bt [N,K] bf16
__global__ void wt_kernel(const float* __restrict__ Wsrc, unsigned short* __restrict__ Bt,
                          int K, int N) {
    int id = blockIdx.x * blockDim.x + threadIdx.x;
    if (id >= K * N) return;
    int n = id % N, k = id / N;
    Bt[(size_t)n * K + k] = f2bf(Wsrc[(size_t)k * N + n]);
}

// ---------- Cheb gather (bf16 table, fp32 accumulate): T = alpha*prop(tb) + beta*base ----------
__global__ __launch_bounds__(256) void gather_cheb_bf(
        const unsigned short* __restrict__ tb, const int* __restrict__ rowptr,
        const int* __restrict__ col, const float* __restrict__ ew,
        const unsigned short* __restrict__ base, float alpha, float beta,
        unsigned short* __restrict__ outc, unsigned short* __restrict__ tslice, int n) {
    int w = (blockIdx.x * blockDim.x + threadIdx.x) >> 6;
    int lane = threadIdx.x & 63;
    if (w >= n) return;
    float a0 = 0.0f, a1 = 0.0f;
    int rs = rowptr[w], re = rowptr[w + 1];
    for (int b = rs; b < re; b += 64) {
        int cl = 0; float wl = 0.0f;
        if (b + lane < re) { cl = col[b + lane]; wl = ew[b + lane]; }
        int nk = min(64, re - b);
        for (int j = 0; j < nk; j++) {
            int s = __shfl(cl, j);
            float we = __shfl(wl, j);
            unsigned u = ((const unsigned*)(tb + (size_t)s * F_IN))[lane];
            a0 += we * bf_lo(u);
            a1 += we * bf_hi(u);
        }
    }
    if (base) {
        unsigned ub = ((const unsigned*)(base + (size_t)w * F_IN))[lane];
        a0 = alpha * a0 + beta * bf_lo(ub);
        a1 = alpha * a1 + beta * bf_hi(ub);
    } else {
        a0 *= alpha; a1 *= alpha;
    }
    ushort2 o; o.x = f2bf(a0); o.y = f2bf(a1);
    *(ushort2*)(outc + (size_t)w * F_IN + lane * 2) = o;
    *(ushort2*)(tslice + (size_t)w * (K_CHEB * F_IN) + lane * 2) = o;
}

// ---------- GCN pre-aggregation (bf16 in/out): z = agg(nrm*tb[col]) + dinv^2*tb[self] ----------
template<int FPL>   // C = FPL*64, FPL in {2,4}
__global__ __launch_bounds__(256) void gather_gcn_pre(
        const unsigned short* __restrict__ tb, const int* __restrict__ rowptr,
        const int* __restrict__ col, const float* __restrict__ ew,
        const float* __restrict__ dinv, unsigned short* __restrict__ z, int n) {
    const int C = FPL * 64;
    int w = (blockIdx.x * blockDim.x + threadIdx.x) >> 6;
    int lane = threadIdx.x & 63;
    if (w >= n) return;
    float acc[FPL];
    #pragma unroll
    for (int q = 0; q < FPL; q++) acc[q] = 0.0f;
    int rs = rowptr[w], re = rowptr[w + 1];
    for (int b = rs; b < re; b += 64) {
        int cl = 0; float wl = 0.0f;
        if (b + lane < re) { cl = col[b + lane]; wl = ew[b + lane]; }
        int nk = min(64, re - b);
        for (int j = 0; j < nk; j++) {
            int s = __shfl(cl, j);
            float we = __shfl(wl, j);
            if constexpr (FPL == 2) {
                unsigned u = ((const unsigned*)(tb + (size_t)s * C))[lane];
                acc[0] += we * bf_lo(u);
                acc[1] += we * bf_hi(u);
            } else {
                uint2 u = ((const uint2*)(tb + (size_t)s * C))[lane];
                acc[0] += we * bf_lo(u.x); acc[1] += we * bf_hi(u.x);
                acc[2] += we * bf_lo(u.y); acc[3] += we * bf_hi(u.y);
            }
        }
    }
    float sn = dinv[w] * dinv[w];
    if constexpr (FPL == 2) {
        unsigned u = ((const unsigned*)(tb + (size_t)w * C))[lane];
        acc[0] += sn * bf_lo(u); acc[1] += sn * bf_hi(u);
        ushort2 o; o.x = f2bf(acc[0]); o.y = f2bf(acc[1]);
        *(ushort2*)(z + (size_t)w * C + lane * 2) = o;
    } else {
        uint2 u = ((const uint2*)(tb + (size_t)w * C))[lane];
        acc[0] += sn * bf_lo(u.x); acc[1] += sn * bf_hi(u.x);
        acc[2] += sn * bf_lo(u.y); acc[3] += sn * bf_hi(u.y);
        ushort4 o; o.x = f2bf(acc[0]); o.y = f2bf(acc[1]);
        o.z = f2bf(acc[2]); o.w = f2bf(acc[3]);
        *(ushort4*)(z + (size_t)w * C + lane * 4) = o;
    }
}

// ---------- bf16 MFMA GEMM: C[M,N] = relu(A[M,K] @ Bt[N,K]^T + bias) ----------
// 128x128 block tile, 4 waves (2x2), each wave 64x64 = 4x4 MFMA tiles of 16x16x32.
// Fragments loaded directly from global (A rows / Bt rows contiguous in K).
__global__ __launch_bounds__(256) void gemm_bf16(
        const unsigned short* __restrict__ A, const unsigned short* __restrict__ Bt,
        const float* __restrict__ bias, float* __restrict__ Cf,
        unsigned short* __restrict__ Cb, int M, int K, int N, int relu) {
    int m0 = blockIdx.y * 128, n0 = blockIdx.x * 128;
    int wave = threadIdx.x >> 6, lane = threadIdx.x & 63;
    int wm = (wave & 1) * 64, wn = (wave >> 1) * 64;
    int l15 = lane & 15, quad = lane >> 4;

    v4f acc[4][4];
    #pragma unroll
    for (int i = 0; i < 4; i++)
        #pragma unroll
        for (int j = 0; j < 4; j++) acc[i][j] = (v4f){0.f, 0.f, 0.f, 0.f};

    const unsigned short* Ab[4]; bool av[4];
    #pragma unroll
    for (int i = 0; i < 4; i++) {
        int row = m0 + wm + i * 16 + l15;
        av[i] = row < M;
        Ab[i] = A + (size_t)(av[i] ? row : 0) * K + quad * 8;
    }
    const unsigned short* Bb[4];
    #pragma unroll
    for (int j = 0; j < 4; j++) {
        int coln = n0 + wn + j * 16 + l15;
        Bb[j] = Bt + (size_t)coln * K + quad * 8;
    }
    const v8s zero8 = {0, 0, 0, 0, 0, 0, 0, 0};

    for (int k0 = 0; k0 < K; k0 += 32) {
        v8s a[4], b[4];
        #pragma unroll
        for (int i = 0; i < 4; i++) a[i] = av[i] ? *(const v8s*)(Ab[i] + k0) : zero8;
        #pragma unroll
        for (int j = 0; j < 4; j++) b[j] = *(const v8s*)(Bb[j] + k0);
        #pragma unroll
        for (int i = 0; i < 4; i++)
            #pragma unroll
            for (int j = 0; j < 4; j++)
                acc[i][j] = __builtin_amdgcn_mfma_f32_16x16x32_bf16(a[i], b[j], acc[i][j], 0, 0, 0);
    }

    #pragma unroll
    for (int j = 0; j < 4; j++) {
        int coln = n0 + wn + j * 16 + l15;
        float bv = bias ? bias[coln] : 0.0f;
        #pragma unroll
        for (int i = 0; i < 4; i++) {
            int rbase = m0 + wm + i * 16 + quad * 4;
            #pragma unroll
            for (int r = 0; r < 4; r++) {
                int row = rbase + r;
                if (row >= M) continue;
                float v = acc[i][j][r] + bv;
                if (relu) v = fmaxf(v, 0.0f);
                if (Cf) Cf[(size_t)row * N + coln] = v;
                else    Cb[(size_t)row * N + coln] = f2bf(v);
            }
        }
    }
}

// ---------- gate: logits[n] = h3[n,:] . w_gate + b ----------
__global__ void gate_kernel(const float* __restrict__ h3, const float* __restrict__ wg,
                            const float* __restrict__ bg, float* __restrict__ logits, int n) {
    int node = blockIdx.x * 4 + (threadIdx.x >> 6);
    int lane = threadIdx.x & 63;
    if (node >= n) return;
    float s = 0.0f;
    #pragma unroll
    for (int i = 0; i < 8; i++) {
        int c = i * 64 + lane;
        s += h3[(size_t)node * C3_DIM + c] * wg[c];
    }
    #pragma unroll
    for (int off = 32; off > 0; off >>= 1) s += __shfl_down(s, off);
    if (lane == 0) logits[node] = s + bg[0];
}

// ---------- graph boundaries from sorted batch ----------
__global__ void gptr_kernel(const int* __restrict__ batch, int* __restrict__ gptr, int n) {
    int i = blockIdx.x * blockDim.x + threadIdx.x;
    if (i >= n) return;
    int b = batch[i];
    if (i == 0) { for (int g = 0; g <= b; g++) gptr[g] = 0; }
    else {
        int bp = batch[i - 1];
        for (int g = bp + 1; g <= b; g++) gptr[g] = i;
    }
    if (i == n - 1) { for (int g = b + 1; g <= N_GRAPHS; g++) gptr[g] = n; }
}

// ---------- fused attention pool (no atomics): block = (graph, 256-feat chunk) ----------
__global__ __launch_bounds__(256) void pool_fused(const float* __restrict__ h3,
        const float* __restrict__ logits, const int* __restrict__ gptr,
        float* __restrict__ pooled) {
    __shared__ float red[256];
    int g = blockIdx.x, ch = blockIdx.y, tid = threadIdx.x;
    int gs = gptr[g], ge = gptr[g + 1];
    // max
    float m = -INFINITY;
    for (int i = gs + tid; i < ge; i += 256) m = fmaxf(m, logits[i]);
    red[tid] = m; __syncthreads();
    for (int off = 128; off > 0; off >>= 1) {
        if (tid < off) red[tid] = fmaxf(red[tid], red[tid + off]);
        __syncthreads();
    }
    m = red[0]; __syncthreads();
    // sum exp
    float s = 0.0f;
    for (int i = gs + tid; i < ge; i += 256) s += expf(logits[i] - m);
    red[tid] = s; __syncthreads();
    for (int off = 128; off > 0; off >>= 1) {
        if (tid < off) red[tid] += red[tid + off];
        __syncthreads();
    }
    s = red[0];
    // weighted feature sum
    int c = ch * 256 + tid;
    float acc = 0.0f;
    for (int i = gs; i < ge; i++) {
        float alpha = expf(logits[i] - m);
        acc += alpha * h3[(size_t)i * C3_DIM + c];
    }
    pooled[(size_t)g * C3_DIM + c] = (ge > gs) ? acc / s : 0.0f;
}

// ---------- FC + log_softmax ----------
__global__ void fc_kernel(const float* __restrict__ pooled, const float* __restrict__ Wfc,
                          const float* __restrict__ bfc, float* __restrict__ out) {
    int g = blockIdx.x;
    int t = threadIdx.x;
    float acc = -INFINITY;
    if (t < NCLS) {
        acc = bfc[t];
        for (int k = 0; k < C3_DIM; k++)
            acc += pooled[(size_t)g * C3_DIM + k] * Wfc[k * NCLS + t];
    }
    float m = acc;
    #pragma unroll
    for (int off = 8; off > 0; off >>= 1) m = fmaxf(m, __shfl_xor(m, off, 16));
    float e = (t < NCLS) ? expf(acc - m) : 0.0f;
    float s = e;
    #pragma unroll
    for (int off = 8; off > 0; off >>= 1) s += __shfl_xor(s, off, 16);
    if (t < NCLS) out[g * NCLS + t] = acc - m - logf(s);
}

// ---------- host ----------
extern "C" void kernel_launch(void* const* d_in, const int* in_sizes, int n_in,
                              void* d_out, int out_size, void* d_ws, size_t ws_size,
                              hipStream_t stream) {
    const float* x      = (const float*)d_in[0];
    const int*   ei     = (const int*)d_in[1];
    const int*   batch  = (const int*)d_in[2];
    const float* W_cheb = (const float*)d_in[3];
    const float* b_cheb = (const float*)d_in[4];
    const float* W_g1   = (const float*)d_in[5];
    const float* b_g1   = (const float*)d_in[6];
    const float* W_g2   = (const float*)d_in[7];
    const float* b_g2   = (const float*)d_in[8];
    const float* w_gate = (const float*)d_in[9];
    const float* b_gate = (const float*)d_in[10];
    const float* W_fc   = (const float*)d_in[11];
    const float* b_fc   = (const float*)d_in[12];
    const int* src = ei;
    const int* dst = ei + N_EDGES;
    float* out = (float*)d_out;

    const int N = N_NODES, E = N_EDGES, G = N_GRAPHS;

    char* Wp = (char*)d_ws;
    auto alloc = [&](size_t bytes) {
        void* p = Wp;
        Wp += (bytes + 255) & ~(size_t)255;
        return p;
    };
    int*   cnt_s   = (int*)alloc(N * 4);
    int*   cnt_d   = (int*)alloc(N * 4);
    int*   fillc   = (int*)alloc(N * 4);
    int*   rowptr  = (int*)alloc((N + 1) * 4);
    int*   col     = (int*)alloc(E * 4);
    float* wch     = (float*)alloc(E * 4);
    float* nrm     = (float*)alloc(E * 4);
    float* dinv_c  = (float*)alloc(N * 4);
    float* dinv_g  = (float*)alloc(N * 4);
    unsigned short* xb    = (unsigned short*)alloc((size_t)N * F_IN * 2);
    unsigned short* t1b   = (unsigned short*)alloc((size_t)N * F_IN * 2);
    unsigned short* t2b   = (unsigned short*)alloc((size_t)N * F_IN * 2);
    unsigned short* t3b   = (unsigned short*)alloc((size_t)N * F_IN * 2);
    unsigned short* t4b   = (unsigned short*)alloc((size_t)N * F_IN * 2);
    unsigned short* tcat  = (unsigned short*)alloc((size_t)N * K_CHEB * F_IN * 2);
    unsigned short* h1b   = (unsigned short*)alloc((size_t)N * C1_DIM * 2);
    unsigned short* z1b   = (unsigned short*)alloc((size_t)N * C1_DIM * 2);
    unsigned short* h2b   = (unsigned short*)alloc((size_t)N * C2_DIM * 2);
    unsigned short* z2b   = (unsigned short*)alloc((size_t)N * C2_DIM * 2);
    float* h3      = (float*)alloc((size_t)N * C3_DIM * 4);
    unsigned short* Wcb_t = (unsigned short*)alloc((size_t)K_CHEB * F_IN * C1_DIM * 2);
    unsigned short* Wg1_t = (unsigned short*)alloc((size_t)C1_DIM * C2_DIM * 2);
    unsigned short* Wg2_t = (unsigned short*)alloc((size_t)C2_DIM * C3_DIM * 2);
    float* logits  = (float*)alloc(N * 4);
    int*   gptr    = (int*)alloc((G + 1) * 4);
    float* pooled  = (float*)alloc((size_t)G * C3_DIM * 4);

    dim3 blk(256);
    auto cdiv = [](int a, int b) { return (a + b - 1) / b; };

    // --- CSR build (dst-sorted) ---
    hipMemsetAsync(cnt_s, 0, 3 * N * sizeof(int), stream);   // cnt_s, cnt_d, fillc (contiguous 256B-aligned blocks? they are separate allocs)
    hipMemsetAsync(cnt_d, 0, N * sizeof(int), stream);
    hipMemsetAsync(fillc, 0, N * sizeof(int), stream);
    hipLaunchKernelGGL(count_kernel, dim3(cdiv(E, 256)), blk, 0, stream, src, dst, cnt_s, cnt_d, E);
    hipLaunchKernelGGL(dinv_kernel, dim3(cdiv(N, 256)), blk, 0, stream, cnt_s, cnt_d, dinv_c, dinv_g, N);
    hipLaunchKernelGGL(scan_kernel, dim3(1), blk, 0, stream, cnt_d, rowptr, N);
    hipLaunchKernelGGL(fill_kernel, dim3(cdiv(E, 256)), blk, 0, stream,
                       src, dst, dinv_c, dinv_g, rowptr, fillc, col, wch, nrm, E);

    // --- converts ---
    hipLaunchKernelGGL(conv_x_kernel, dim3(cdiv(N * 64, 256)), blk, 0, stream, x, xb, tcat);
    hipLaunchKernelGGL(wt_kernel, dim3(cdiv(K_CHEB * F_IN * C1_DIM, 256)), blk, 0, stream,
                       W_cheb, Wcb_t, K_CHEB * F_IN, C1_DIM);
    hipLaunchKernelGGL(wt_kernel, dim3(cdiv(C1_DIM * C2_DIM, 256)), blk, 0, stream,
                       W_g1, Wg1_t, C1_DIM, C2_DIM);
    hipLaunchKernelGGL(wt_kernel, dim3(cdiv(C2_DIM * C3_DIM, 256)), blk, 0, stream,
                       W_g2, Wg2_t, C2_DIM, C3_DIM);

    const int NWB = cdiv(N, 4);   // gathers: 4 waves/block, 1 node/wave
    const int TC = K_CHEB * F_IN;

    // --- Cheb recurrence in bf16, filling Tcat slices ---
    hipLaunchKernelGGL(gather_cheb_bf, dim3(NWB), blk, 0, stream,        // T1 = prop(x)
                       xb, rowptr, col, wch, (const unsigned short*)nullptr, 1.0f, 0.0f,
                       t1b, tcat + 1 * F_IN, N);
    hipLaunchKernelGGL(gather_cheb_bf, dim3(NWB), blk, 0, stream,        // T2 = 2 prop(T1) - T0
                       t1b, rowptr, col, wch, xb, 2.0f, -1.0f, t2b, tcat + 2 * F_IN, N);
    hipLaunchKernelGGL(gather_cheb_bf, dim3(NWB), blk, 0, stream,        // T3
                       t2b, rowptr, col, wch, t1b, 2.0f, -1.0f, t3b, tcat + 3 * F_IN, N);
    hipLaunchKernelGGL(gather_cheb_bf, dim3(NWB), blk, 0, stream,        // T4
                       t3b, rowptr, col, wch, t2b, 2.0f, -1.0f, t4b, tcat + 4 * F_IN, N);

    // --- GEMM1: h1 = relu(Tcat @ Wcheb + b_cheb)  [10000,640]x[640,128] -> bf16 ---
    hipLaunchKernelGGL(gemm_bf16, dim3(C1_DIM / 128, cdiv(N, 128)), blk, 0, stream,
                       tcat, Wcb_t, b_cheb, (float*)nullptr, h1b, N, TC, C1_DIM, 1);

    // --- GCN1: pre-aggregate in C1 space, then GEMM ---
    hipLaunchKernelGGL(gather_gcn_pre<2>, dim3(NWB), blk, 0, stream,
                       h1b, rowptr, col, nrm, dinv_g, z1b, N);
    hipLaunchKernelGGL(gemm_bf16, dim3(C2_DIM / 128, cdiv(N, 128)), blk, 0, stream,
                       z1b, Wg1_t, b_g1, (float*)nullptr, h2b, N, C1_DIM, C2_DIM, 1);

    // --- GCN2 ---
    hipLaunchKernelGGL(gather_gcn_pre<4>, dim3(NWB), blk, 0, stream,
                       h2b, rowptr, col, nrm, dinv_g, z2b, N);
    hipLaunchKernelGGL(gemm_bf16, dim3(C3_DIM / 128, cdiv(N, 128)), blk, 0, stream,
                       z2b, Wg2_t, b_g2, h3, (unsigned short*)nullptr, N, C2_DIM, C3_DIM, 1);

    // --- attention pool (atomic-free) ---
    hipLaunchKernelGGL(gate_kernel, dim3(cdiv(N, 4)), blk, 0, stream, h3, w_gate, b_gate, logits, N);
    hipLaunchKernelGGL(gptr_kernel, dim3(cdiv(N, 256)), blk, 0, stream, batch, gptr, N);
    hipLaunchKernelGGL(pool_fused, dim3(G, C3_DIM / 256), blk, 0, stream, h3, logits, gptr, pooled);

    // --- FC + log_softmax ---
    hipLaunchKernelGGL(fc_kernel, dim3(G), dim3(64), 0, stream, pooled, W_fc, b_fc, out);
}

// Round 4
// 320.083 us; speedup vs baseline: 9.8640x; 1.2906x over previous
//
#include <hip/hip_runtime.h>
#include <hip/hip_bf16.h>
#include <math.h>

#define N_NODES 10000
#define N_EDGES 160000
#define N_GRAPHS 64
#define F_IN    128
#define C1_DIM  128
#define C2_DIM  256
#define C3_DIM  512
#define K_CHEB  5
#define NCLS    10

typedef short v8s __attribute__((ext_vector_type(8)));
typedef float v4f __attribute__((ext_vector_type(4)));

// ---------- bf16 helpers ----------
static __device__ __forceinline__ unsigned short f2bf(float f) {
    unsigned u = __float_as_uint(f);
    unsigned r = (u + 0x7FFFu + ((u >> 16) & 1u)) >> 16;   // RNE
    return (unsigned short)r;
}
static __device__ __forceinline__ float bf_lo(unsigned u) { return __uint_as_float(u << 16); }
static __device__ __forceinline__ float bf_hi(unsigned u) { return __uint_as_float(u & 0xFFFF0000u); }

// ---------- CSR build ----------
__global__ void count_kernel(const int* __restrict__ src, const int* __restrict__ dst,
                             int* __restrict__ cnt_s, int* __restrict__ cnt_d, int E) {
    int e = blockIdx.x * blockDim.x + threadIdx.x;
    if (e >= E) return;
    atomicAdd(&cnt_s[src[e]], 1);
    atomicAdd(&cnt_d[dst[e]], 1);
}

__global__ void dinv_kernel(const int* __restrict__ cnt_s, const int* __restrict__ cnt_d,
                            float* __restrict__ dinv_c, float* __restrict__ dinv_g, int n) {
    int i = blockIdx.x * blockDim.x + threadIdx.x;
    if (i >= n) return;
    int cs = cnt_s[i];
    dinv_c[i] = (cs > 0) ? rsqrtf((float)cs) : 0.0f;
    dinv_g[i] = rsqrtf((float)cnt_d[i] + 1.0f);   // GCN self-loop -> deg >= 1
}

// single-block exclusive scan: each thread owns a contiguous chunk; one 8-step LDS scan
__global__ __launch_bounds__(256) void scan_kernel(const int* __restrict__ cnt,
                                                   int* __restrict__ rowptr, int n) {
    __shared__ int sums[256];
    int tid = threadIdx.x;
    int chunk = (n + 255) / 256;
    int s0 = tid * chunk, s1 = min(n, s0 + chunk);
    int loc = 0;
    for (int i = s0; i < s1; i++) loc += cnt[i];
    sums[tid] = loc;
    __syncthreads();
    for (int off = 1; off < 256; off <<= 1) {
        int t = (tid >= off) ? sums[tid - off] : 0;
        __syncthreads();
        sums[tid] += t;
        __syncthreads();
    }
    int pre = sums[tid] - loc;   // exclusive prefix of this chunk
    for (int i = s0; i < s1; i++) { rowptr[i] = pre; pre += cnt[i]; }
    if (tid == 255) rowptr[n] = pre;
}

__global__ void fill_kernel(const int* __restrict__ src, const int* __restrict__ dst,
                            const float* __restrict__ dinv_c, const float* __restrict__ dinv_g,
                            const int* __restrict__ rowptr, int* __restrict__ fillc,
                            int* __restrict__ col, float* __restrict__ wch,
                            float* __restrict__ nrm, int E) {
    int e = blockIdx.x * blockDim.x + threadIdx.x;
    if (e >= E) return;
    int s = src[e], d = dst[e];
    int pos = rowptr[d] + atomicAdd(&fillc[d], 1);
    col[pos] = s;
    wch[pos] = -(dinv_c[s] * dinv_c[d]);
    nrm[pos] = dinv_g[s] * dinv_g[d];
}

// ---------- converts ----------
__global__ void conv_x_kernel(const float* __restrict__ x, unsigned short* __restrict__ xb,
                              unsigned short* __restrict__ tcat) {
    int id = blockIdx.x * blockDim.x + threadIdx.x;
    if (id >= N_NODES * 64) return;
    int n = id >> 6, f = (id & 63) * 2;
    float2 v = *(const float2*)(x + (size_t)n * F_IN + f);
    ushort2 o; o.x = f2bf(v.x); o.y = f2bf(v.y);
    *(ushort2*)(xb + (size_t)n * F_IN + f) = o;
    *(ushort2*)(tcat + (size_t)n * (K_CHEB * F_IN) + f) = o;
}

// W [K,N] fp32 row-major -> Bt [N,K] bf16
__global__ void wt_kernel(const float* __restrict__ Wsrc, unsigned short* __restrict__ Bt,
                          int K, int N) {
    int id = blockIdx.x * blockDim.x + threadIdx.x;
    if (id >= K * N) return;
    int n = id % N, k = id / N;
    Bt[(size_t)n * K + k] = f2bf(Wsrc[(size_t)k * N + n]);
}

// ---------- Cheb gather (bf16 table, fp32 acc), 4x edge-unrolled ----------
__global__ __launch_bounds__(256) void gather_cheb_bf(
        const unsigned short* __restrict__ tb, const int* __restrict__ rowptr,
        const int* __restrict__ col, const float* __restrict__ ew,
        const unsigned short* __restrict__ base, float alpha, float beta,
        unsigned short* __restrict__ outc, unsigned short* __restrict__ tslice, int n) {
    int w = (blockIdx.x * blockDim.x + threadIdx.x) >> 6;
    int lane = threadIdx.x & 63;
    if (w >= n) return;
    float a0 = 0.0f, a1 = 0.0f;
    int rs = rowptr[w], re = rowptr[w + 1];
    for (int b = rs; b < re; b += 64) {
        int cl = 0; float wl = 0.0f;
        if (b + lane < re) { cl = col[b + lane]; wl = ew[b + lane]; }
        int nk4 = (min(64, re - b) + 3) & ~3;   // pad: lanes >= nk hold cl=0, wl=0
        for (int j = 0; j < nk4; j += 4) {
            int s0 = __shfl(cl, j), s1 = __shfl(cl, j + 1);
            int s2 = __shfl(cl, j + 2), s3 = __shfl(cl, j + 3);
            float w0 = __shfl(wl, j), w1 = __shfl(wl, j + 1);
            float w2 = __shfl(wl, j + 2), w3 = __shfl(wl, j + 3);
            unsigned u0 = ((const unsigned*)(tb + (size_t)s0 * F_IN))[lane];
            unsigned u1 = ((const unsigned*)(tb + (size_t)s1 * F_IN))[lane];
            unsigned u2 = ((const unsigned*)(tb + (size_t)s2 * F_IN))[lane];
            unsigned u3 = ((const unsigned*)(tb + (size_t)s3 * F_IN))[lane];
            a0 += w0 * bf_lo(u0) + w1 * bf_lo(u1) + w2 * bf_lo(u2) + w3 * bf_lo(u3);
            a1 += w0 * bf_hi(u0) + w1 * bf_hi(u1) + w2 * bf_hi(u2) + w3 * bf_hi(u3);
        }
    }
    if (base) {
        unsigned ub = ((const unsigned*)(base + (size_t)w * F_IN))[lane];
        a0 = alpha * a0 + beta * bf_lo(ub);
        a1 = alpha * a1 + beta * bf_hi(ub);
    } else {
        a0 *= alpha; a1 *= alpha;
    }
    ushort2 o; o.x = f2bf(a0); o.y = f2bf(a1);
    *(ushort2*)(outc + (size_t)w * F_IN + lane * 2) = o;
    *(ushort2*)(tslice + (size_t)w * (K_CHEB * F_IN) + lane * 2) = o;
}

// ---------- GCN pre-aggregation (bf16 in/out), 4x edge-unrolled ----------
template<int FPL>   // C = FPL*64, FPL in {2,4}
__global__ __launch_bounds__(256) void gather_gcn_pre(
        const unsigned short* __restrict__ tb, const int* __restrict__ rowptr,
        const int* __restrict__ col, const float* __restrict__ ew,
        const float* __restrict__ dinv, unsigned short* __restrict__ z, int n) {
    const int C = FPL * 64;
    int w = (blockIdx.x * blockDim.x + threadIdx.x) >> 6;
    int lane = threadIdx.x & 63;
    if (w >= n) return;
    float acc[FPL];
    #pragma unroll
    for (int q = 0; q < FPL; q++) acc[q] = 0.0f;
    int rs = rowptr[w], re = rowptr[w + 1];
    for (int b = rs; b < re; b += 64) {
        int cl = 0; float wl = 0.0f;
        if (b + lane < re) { cl = col[b + lane]; wl = ew[b + lane]; }
        int nk4 = (min(64, re - b) + 3) & ~3;
        for (int j = 0; j < nk4; j += 4) {
            int s0 = __shfl(cl, j), s1 = __shfl(cl, j + 1);
            int s2 = __shfl(cl, j + 2), s3 = __shfl(cl, j + 3);
            float w0 = __shfl(wl, j), w1 = __shfl(wl, j + 1);
            float w2 = __shfl(wl, j + 2), w3 = __shfl(wl, j + 3);
            if constexpr (FPL == 2) {
                unsigned u0 = ((const unsigned*)(tb + (size_t)s0 * C))[lane];
                unsigned u1 = ((const unsigned*)(tb + (size_t)s1 * C))[lane];
                unsigned u2 = ((const unsigned*)(tb + (size_t)s2 * C))[lane];
                unsigned u3 = ((const unsigned*)(tb + (size_t)s3 * C))[lane];
                acc[0] += w0 * bf_lo(u0) + w1 * bf_lo(u1) + w2 * bf_lo(u2) + w3 * bf_lo(u3);
                acc[1] += w0 * bf_hi(u0) + w1 * bf_hi(u1) + w2 * bf_hi(u2) + w3 * bf_hi(u3);
            } else {
                uint2 u0 = ((const uint2*)(tb + (size_t)s0 * C))[lane];
                uint2 u1 = ((const uint2*)(tb + (size_t)s1 * C))[lane];
                uint2 u2 = ((const uint2*)(tb + (size_t)s2 * C))[lane];
                uint2 u3 = ((const uint2*)(tb + (size_t)s3 * C))[lane];
                acc[0] += w0 * bf_lo(u0.x) + w1 * bf_lo(u1.x) + w2 * bf_lo(u2.x) + w3 * bf_lo(u3.x);
                acc[1] += w0 * bf_hi(u0.x) + w1 * bf_hi(u1.x) + w2 * bf_hi(u2.x) + w3 * bf_hi(u3.x);
                acc[2] += w0 * bf_lo(u0.y) + w1 * bf_lo(u1.y) + w2 * bf_lo(u2.y) + w3 * bf_lo(u3.y);
                acc[3] += w0 * bf_hi(u0.y) + w1 * bf_hi(u1.y) + w2 * bf_hi(u2.y) + w3 * bf_hi(u3.y);
            }
        }
    }
    float sn = dinv[w] * dinv[w];
    if constexpr (FPL == 2) {
        unsigned u = ((const unsigned*)(tb + (size_t)w * C))[lane];
        acc[0] += sn * bf_lo(u); acc[1] += sn * bf_hi(u);
        ushort2 o; o.x = f2bf(acc[0]); o.y = f2bf(acc[1]);
        *(ushort2*)(z + (size_t)w * C + lane * 2) = o;
    } else {
        uint2 u = ((const uint2*)(tb + (size_t)w * C))[lane];
        acc[0] += sn * bf_lo(u.x); acc[1] += sn * bf_hi(u.x);
        acc[2] += sn * bf_lo(u.y); acc[3] += sn * bf_hi(u.y);
        ushort4 o; o.x = f2bf(acc[0]); o.y = f2bf(acc[1]);
        o.z = f2bf(acc[2]); o.w = f2bf(acc[3]);
        *(ushort4*)(z + (size_t)w * C + lane * 4) = o;
    }
}

// ---------- bf16 MFMA GEMM: C[M,N] = relu(A[M,K] @ Bt[N,K]^T + bias) ----------
__global__ __launch_bounds__(256) void gemm_bf16(
        const unsigned short* __restrict__ A, const unsigned short* __restrict__ Bt,
        const float* __restrict__ bias, float* __restrict__ Cf,
        unsigned short* __restrict__ Cb, int M, int K, int N, int relu) {
    int m0 = blockIdx.y * 128, n0 = blockIdx.x * 128;
    int wave = threadIdx.x >> 6, lane = threadIdx.x & 63;
    int wm = (wave & 1) * 64, wn = (wave >> 1) * 64;
    int l15 = lane & 15, quad = lane >> 4;

    v4f acc[4][4];
    #pragma unroll
    for (int i = 0; i < 4; i++)
        #pragma unroll
        for (int j = 0; j < 4; j++) acc[i][j] = (v4f){0.f, 0.f, 0.f, 0.f};

    const unsigned short* Ab[4]; bool av[4];
    #pragma unroll
    for (int i = 0; i < 4; i++) {
        int row = m0 + wm + i * 16 + l15;
        av[i] = row < M;
        Ab[i] = A + (size_t)(av[i] ? row : 0) * K + quad * 8;
    }
    const unsigned short* Bb[4];
    #pragma unroll
    for (int j = 0; j < 4; j++) {
        int coln = n0 + wn + j * 16 + l15;
        Bb[j] = Bt + (size_t)coln * K + quad * 8;
    }
    const v8s zero8 = {0, 0, 0, 0, 0, 0, 0, 0};

    for (int k0 = 0; k0 < K; k0 += 32) {
        v8s a[4], b[4];
        #pragma unroll
        for (int i = 0; i < 4; i++) a[i] = av[i] ? *(const v8s*)(Ab[i] + k0) : zero8;
        #pragma unroll
        for (int j = 0; j < 4; j++) b[j] = *(const v8s*)(Bb[j] + k0);
        #pragma unroll
        for (int i = 0; i < 4; i++)
            #pragma unroll
            for (int j = 0; j < 4; j++)
                acc[i][j] = __builtin_amdgcn_mfma_f32_16x16x32_bf16(a[i], b[j], acc[i][j], 0, 0, 0);
    }

    #pragma unroll
    for (int j = 0; j < 4; j++) {
        int coln = n0 + wn + j * 16 + l15;
        float bv = bias ? bias[coln] : 0.0f;
        #pragma unroll
        for (int i = 0; i < 4; i++) {
            int rbase = m0 + wm + i * 16 + quad * 4;
            #pragma unroll
            for (int r = 0; r < 4; r++) {
                int row = rbase + r;
                if (row >= M) continue;
                float v = acc[i][j][r] + bv;
                if (relu) v = fmaxf(v, 0.0f);
                if (Cf) Cf[(size_t)row * N + coln] = v;
                else    Cb[(size_t)row * N + coln] = f2bf(v);
            }
        }
    }
}

// ---------- gate ----------
__global__ void gate_kernel(const float* __restrict__ h3, const float* __restrict__ wg,
                            const float* __restrict__ bg, float* __restrict__ logits, int n) {
    int node = blockIdx.x * 4 + (threadIdx.x >> 6);
    int lane = threadIdx.x & 63;
    if (node >= n) return;
    float s = 0.0f;
    #pragma unroll
    for (int i = 0; i < 8; i++) {
        int c = i * 64 + lane;
        s += h3[(size_t)node * C3_DIM + c] * wg[c];
    }
    #pragma unroll
    for (int off = 32; off > 0; off >>= 1) s += __shfl_down(s, off);
    if (lane == 0) logits[node] = s + bg[0];
}

// ---------- graph boundaries from sorted batch ----------
__global__ void gptr_kernel(const int* __restrict__ batch, int* __restrict__ gptr, int n) {
    int i = blockIdx.x * blockDim.x + threadIdx.x;
    if (i >= n) return;
    int b = batch[i];
    if (i == 0) { for (int g = 0; g <= b; g++) gptr[g] = 0; }
    else {
        int bp = batch[i - 1];
        for (int g = bp + 1; g <= b; g++) gptr[g] = i;
    }
    if (i == n - 1) { for (int g = b + 1; g <= N_GRAPHS; g++) gptr[g] = n; }
}

// ---------- pool phase A: per-graph softmax stats; overwrite logits with alpha ----------
__global__ __launch_bounds__(256) void pool_stats(float* __restrict__ logits,
                                                  const int* __restrict__ gptr) {
    __shared__ float red[256];
    int g = blockIdx.x, tid = threadIdx.x;
    int gs = gptr[g], ge = gptr[g + 1];
    float m = -INFINITY;
    for (int i = gs + tid; i < ge; i += 256) m = fmaxf(m, logits[i]);
    red[tid] = m; __syncthreads();
    for (int off = 128; off > 0; off >>= 1) {
        if (tid < off) red[tid] = fmaxf(red[tid], red[tid + off]);
        __syncthreads();
    }
    m = red[0]; __syncthreads();
    float s = 0.0f;
    for (int i = gs + tid; i < ge; i += 256) s += expf(logits[i] - m);
    red[tid] = s; __syncthreads();
    for (int off = 128; off > 0; off >>= 1) {
        if (tid < off) red[tid] += red[tid + off];
        __syncthreads();
    }
    s = red[0];
    float sinv = (s > 0.0f) ? 1.0f / s : 0.0f;
    for (int i = gs + tid; i < ge; i += 256)
        logits[i] = expf(logits[i] - m) * sinv;   // alpha
}

// ---------- pool phase B: grid (G, C3/256, 8 slices), atomicAdd partials ----------
__global__ __launch_bounds__(256) void pool_partial(const float* __restrict__ h3,
        const float* __restrict__ alpha, const int* __restrict__ gptr,
        float* __restrict__ pooled) {
    int g = blockIdx.x, ch = blockIdx.y, sl = blockIdx.z;
    int gs = gptr[g], ge = gptr[g + 1];
    int cnt = ge - gs;
    int i0 = gs + (cnt * sl) / 8;
    int i1 = gs + (cnt * (sl + 1)) / 8;
    int c = ch * 256 + threadIdx.x;
    float acc = 0.0f;
    for (int i = i0; i < i1; i++)
        acc += alpha[i] * h3[(size_t)i * C3_DIM + c];
    if (i1 > i0) atomicAdd(&pooled[(size_t)g * C3_DIM + c], acc);
}

// ---------- FC + log_softmax ----------
__global__ void fc_kernel(const float* __restrict__ pooled, const float* __restrict__ Wfc,
                          const float* __restrict__ bfc, float* __restrict__ out) {
    int g = blockIdx.x;
    int t = threadIdx.x;
    float acc = -INFINITY;
    if (t < NCLS) {
        acc = bfc[t];
        for (int k = 0; k < C3_DIM; k++)
            acc += pooled[(size_t)g * C3_DIM + k] * Wfc[k * NCLS + t];
    }
    float m = acc;
    #pragma unroll
    for (int off = 8; off > 0; off >>= 1) m = fmaxf(m, __shfl_xor(m, off, 16));
    float e = (t < NCLS) ? expf(acc - m) : 0.0f;
    float s = e;
    #pragma unroll
    for (int off = 8; off > 0; off >>= 1) s += __shfl_xor(s, off, 16);
    if (t < NCLS) out[g * NCLS + t] = acc - m - logf(s);
}

// ---------- host ----------
extern "C" void kernel_launch(void* const* d_in, const int* in_sizes, int n_in,
                              void* d_out, int out_size, void* d_ws, size_t ws_size,
                              hipStream_t stream) {
    const float* x      = (const float*)d_in[0];
    const int*   ei     = (const int*)d_in[1];
    const int*   batch  = (const int*)d_in[2];
    const float* W_cheb = (const float*)d_in[3];
    const float* b_cheb = (const float*)d_in[4];
    const float* W_g1   = (const float*)d_in[5];
    const float* b_g1   = (const float*)d_in[6];
    const float* W_g2   = (const float*)d_in[7];
    const float* b_g2   = (const float*)d_in[8];
    const float* w_gate = (const float*)d_in[9];
    const float* b_gate = (const float*)d_in[10];
    const float* W_fc   = (const float*)d_in[11];
    const float* b_fc   = (const float*)d_in[12];
    const int* src = ei;
    const int* dst = ei + N_EDGES;
    float* out = (float*)d_out;

    const int N = N_NODES, E = N_EDGES, G = N_GRAPHS;

    char* Wp = (char*)d_ws;
    auto alloc = [&](size_t bytes) {
        void* p = Wp;
        Wp += (bytes + 255) & ~(size_t)255;
        return p;
    };
    int*   cnt_s   = (int*)alloc(N * 4);
    int*   cnt_d   = (int*)alloc(N * 4);
    int*   fillc   = (int*)alloc(N * 4);
    int*   rowptr  = (int*)alloc((N + 1) * 4);
    int*   col     = (int*)alloc(E * 4);
    float* wch     = (float*)alloc(E * 4);
    float* nrm     = (float*)alloc(E * 4);
    float* dinv_c  = (float*)alloc(N * 4);
    float* dinv_g  = (float*)alloc(N * 4);
    unsigned short* xb    = (unsigned short*)alloc((size_t)N * F_IN * 2);
    unsigned short* t1b   = (unsigned short*)alloc((size_t)N * F_IN * 2);
    unsigned short* t2b   = (unsigned short*)alloc((size_t)N * F_IN * 2);
    unsigned short* t3b   = (unsigned short*)alloc((size_t)N * F_IN * 2);
    unsigned short* t4b   = (unsigned short*)alloc((size_t)N * F_IN * 2);
    unsigned short* tcat  = (unsigned short*)alloc((size_t)N * K_CHEB * F_IN * 2);
    unsigned short* h1b   = (unsigned short*)alloc((size_t)N * C1_DIM * 2);
    unsigned short* z1b   = (unsigned short*)alloc((size_t)N * C1_DIM * 2);
    unsigned short* h2b   = (unsigned short*)alloc((size_t)N * C2_DIM * 2);
    unsigned short* z2b   = (unsigned short*)alloc((size_t)N * C2_DIM * 2);
    float* h3      = (float*)alloc((size_t)N * C3_DIM * 4);
    unsigned short* Wcb_t = (unsigned short*)alloc((size_t)K_CHEB * F_IN * C1_DIM * 2);
    unsigned short* Wg1_t = (unsigned short*)alloc((size_t)C1_DIM * C2_DIM * 2);
    unsigned short* Wg2_t = (unsigned short*)alloc((size_t)C2_DIM * C3_DIM * 2);
    float* logits  = (float*)alloc(N * 4);
    int*   gptr    = (int*)alloc((G + 1) * 4);
    float* pooled  = (float*)alloc((size_t)G * C3_DIM * 4);

    dim3 blk(256);
    auto cdiv = [](int a, int b) { return (a + b - 1) / b; };

    // --- CSR build (dst-sorted) ---
    hipMemsetAsync(cnt_s, 0, N * sizeof(int), stream);
    hipMemsetAsync(cnt_d, 0, N * sizeof(int), stream);
    hipMemsetAsync(fillc, 0, N * sizeof(int), stream);
    hipLaunchKernelGGL(count_kernel, dim3(cdiv(E, 256)), blk, 0, stream, src, dst, cnt_s, cnt_d, E);
    hipLaunchKernelGGL(dinv_kernel, dim3(cdiv(N, 256)), blk, 0, stream, cnt_s, cnt_d, dinv_c, dinv_g, N);
    hipLaunchKernelGGL(scan_kernel, dim3(1), blk, 0, stream, cnt_d, rowptr, N);
    hipLaunchKernelGGL(fill_kernel, dim3(cdiv(E, 256)), blk, 0, stream,
                       src, dst, dinv_c, dinv_g, rowptr, fillc, col, wch, nrm, E);

    // --- converts ---
    hipLaunchKernelGGL(conv_x_kernel, dim3(cdiv(N * 64, 256)), blk, 0, stream, x, xb, tcat);
    hipLaunchKernelGGL(wt_kernel, dim3(cdiv(K_CHEB * F_IN * C1_DIM, 256)), blk, 0, stream,
                       W_cheb, Wcb_t, K_CHEB * F_IN, C1_DIM);
    hipLaunchKernelGGL(wt_kernel, dim3(cdiv(C1_DIM * C2_DIM, 256)), blk, 0, stream,
                       W_g1, Wg1_t, C1_DIM, C2_DIM);
    hipLaunchKernelGGL(wt_kernel, dim3(cdiv(C2_DIM * C3_DIM, 256)), blk, 0, stream,
                       W_g2, Wg2_t, C2_DIM, C3_DIM);

    const int NWB = cdiv(N, 4);   // gathers: 4 waves/block, 1 node/wave
    const int TC = K_CHEB * F_IN;

    // --- Cheb recurrence in bf16, filling Tcat slices ---
    hipLaunchKernelGGL(gather_cheb_bf, dim3(NWB), blk, 0, stream,        // T1 = prop(x)
                       xb, rowptr, col, wch, (const unsigned short*)nullptr, 1.0f, 0.0f,
                       t1b, tcat + 1 * F_IN, N);
    hipLaunchKernelGGL(gather_cheb_bf, dim3(NWB), blk, 0, stream,        // T2 = 2 prop(T1) - T0
                       t1b, rowptr, col, wch, xb, 2.0f, -1.0f, t2b, tcat + 2 * F_IN, N);
    hipLaunchKernelGGL(gather_cheb_bf, dim3(NWB), blk, 0, stream,        // T3
                       t2b, rowptr, col, wch, t1b, 2.0f, -1.0f, t3b, tcat + 3 * F_IN, N);
    hipLaunchKernelGGL(gather_cheb_bf, dim3(NWB), blk, 0, stream,        // T4
                       t3b, rowptr, col, wch, t2b, 2.0f, -1.0f, t4b, tcat + 4 * F_IN, N);

    // --- GEMM1: h1 = relu(Tcat @ Wcheb + b_cheb) ---
    hipLaunchKernelGGL(gemm_bf16, dim3(C1_DIM / 128, cdiv(N, 128)), blk, 0, stream,
                       tcat, Wcb_t, b_cheb, (float*)nullptr, h1b, N, TC, C1_DIM, 1);

    // --- GCN1: pre-aggregate in C1 space, then GEMM ---
    hipLaunchKernelGGL(gather_gcn_pre<2>, dim3(NWB), blk, 0, stream,
                       h1b, rowptr, col, nrm, dinv_g, z1b, N);
    hipLaunchKernelGGL(gemm_bf16, dim3(C2_DIM / 128, cdiv(N, 128)), blk, 0, stream,
                       z1b, Wg1_t, b_g1, (float*)nullptr, h2b, N, C1_DIM, C2_DIM, 1);

    // --- GCN2 ---
    hipLaunchKernelGGL(gather_gcn_pre<4>, dim3(NWB), blk, 0, stream,
                       h2b, rowptr, col, nrm, dinv_g, z2b, N);
    hipLaunchKernelGGL(gemm_bf16, dim3(C3_DIM / 128, cdiv(N, 128)), blk, 0, stream,
                       z2b, Wg2_t, b_g2, h3, (unsigned short*)nullptr, N, C2_DIM, C3_DIM, 1);

    // --- attention pool (parallelized, near-atomic-free) ---
    hipLaunchKernelGGL(gate_kernel, dim3(cdiv(N, 4)), blk, 0, stream, h3, w_gate, b_gate, logits, N);
    hipLaunchKernelGGL(gptr_kernel, dim3(cdiv(N, 256)), blk, 0, stream, batch, gptr, N);
    hipLaunchKernelGGL(pool_stats, dim3(G), blk, 0, stream, logits, gptr);
    hipMemsetAsync(pooled, 0, (size_t)G * C3_DIM * sizeof(float), stream);
    hipLaunchKernelGGL(pool_partial, dim3(G, C3_DIM / 256, 8), blk, 0, stream,
                       h3, logits, gptr, pooled);

    // --- FC + log_softmax ---
    hipLaunchKernelGGL(fc_kernel, dim3(G), dim3(64), 0, stream, pooled, W_fc, b_fc, out);
}

// Round 5
// 312.618 us; speedup vs baseline: 10.0995x; 1.0239x over previous
//
#include <hip/hip_runtime.h>
#include <hip/hip_bf16.h>
#include <math.h>

#define N_NODES 10000
#define N_EDGES 160000
#define N_GRAPHS 64
#define F_IN    128
#define C1_DIM  128
#define C2_DIM  256
#define C3_DIM  512
#define K_CHEB  5
#define NCLS    10
#define TC      (K_CHEB * F_IN)    // 640

typedef short v8s __attribute__((ext_vector_type(8)));
typedef float v4f __attribute__((ext_vector_type(4)));

// ---------- bf16 helpers ----------
static __device__ __forceinline__ unsigned short f2bf(float f) {
    unsigned u = __float_as_uint(f);
    unsigned r = (u + 0x7FFFu + ((u >> 16) & 1u)) >> 16;   // RNE
    return (unsigned short)r;
}
static __device__ __forceinline__ float bf_lo(unsigned u) { return __uint_as_float(u << 16); }
static __device__ __forceinline__ float bf_hi(unsigned u) { return __uint_as_float(u & 0xFFFF0000u); }

// ---------- CSR: count ----------
__global__ void count_kernel(const int* __restrict__ src, const int* __restrict__ dst,
                             int* __restrict__ cnt_s, int* __restrict__ cnt_d, int E) {
    int e = blockIdx.x * blockDim.x + threadIdx.x;
    if (e >= E) return;
    atomicAdd(&cnt_s[src[e]], 1);
    atomicAdd(&cnt_d[dst[e]], 1);
}

// ---------- CSR: scan + dinv (single block; each thread owns a contiguous chunk) ----------
__global__ __launch_bounds__(256) void scan_dinv_kernel(
        const int* __restrict__ cnt_s, const int* __restrict__ cnt_d,
        int* __restrict__ rowptr, float* __restrict__ dinv_c, float* __restrict__ dinv_g, int n) {
    __shared__ int sums[256];
    int tid = threadIdx.x;
    int chunk = (n + 255) / 256;
    int s0 = tid * chunk, s1 = min(n, s0 + chunk);
    int loc = 0;
    for (int i = s0; i < s1; i++) {
        int cd = cnt_d[i];
        loc += cd;
        int cs = cnt_s[i];
        dinv_c[i] = (cs > 0) ? rsqrtf((float)cs) : 0.0f;
        dinv_g[i] = rsqrtf((float)cd + 1.0f);          // self-loop -> deg >= 1
    }
    sums[tid] = loc;
    __syncthreads();
    for (int off = 1; off < 256; off <<= 1) {
        int t = (tid >= off) ? sums[tid - off] : 0;
        __syncthreads();
        sums[tid] += t;
        __syncthreads();
    }
    int pre = sums[tid] - loc;
    for (int i = s0; i < s1; i++) { rowptr[i] = pre; pre += cnt_d[i]; }
    if (tid == 255) rowptr[n] = pre;
}

// ---------- CSR: fill ----------
__global__ void fill_kernel(const int* __restrict__ src, const int* __restrict__ dst,
                            const float* __restrict__ dinv_c, const float* __restrict__ dinv_g,
                            const int* __restrict__ rowptr, int* __restrict__ fillc,
                            int* __restrict__ col, float* __restrict__ wch,
                            float* __restrict__ nrm, int E) {
    int e = blockIdx.x * blockDim.x + threadIdx.x;
    if (e >= E) return;
    int s = src[e], d = dst[e];
    int pos = rowptr[d] + atomicAdd(&fillc[d], 1);
    col[pos] = s;
    wch[pos] = -(dinv_c[s] * dinv_c[d]);
    nrm[pos] = dinv_g[s] * dinv_g[d];
}

// ---------- fused prep: x->tcat slice0 (bf16) | 3 weight transposes | gptr ----------
#define PREP_A (N_NODES * 64)            // conv x, 2 floats per item
#define PREP_B (TC * C1_DIM)             // W_cheb  [640,128] -> [128,640]
#define PREP_C (C1_DIM * C2_DIM)         // W_g1
#define PREP_D (C2_DIM * C3_DIM)         // W_g2
#define PREP_TOTAL (PREP_A + PREP_B + PREP_C + PREP_D + N_NODES)
__global__ void prep_kernel(const float* __restrict__ x, unsigned short* __restrict__ tcat,
                            const float* __restrict__ Wcheb, unsigned short* __restrict__ Wcb_t,
                            const float* __restrict__ Wg1, unsigned short* __restrict__ Wg1_t,
                            const float* __restrict__ Wg2, unsigned short* __restrict__ Wg2_t,
                            const int* __restrict__ batch, int* __restrict__ gptr) {
    int id = blockIdx.x * blockDim.x + threadIdx.x;
    if (id < PREP_A) {
        int n = id >> 6, f = (id & 63) * 2;
        float2 v = *(const float2*)(x + (size_t)n * F_IN + f);
        ushort2 o; o.x = f2bf(v.x); o.y = f2bf(v.y);
        *(ushort2*)(tcat + (size_t)n * TC + f) = o;
        return;
    }
    id -= PREP_A;
    if (id < PREP_B) {
        int n = id % C1_DIM, k = id / C1_DIM;
        Wcb_t[(size_t)n * TC + k] = f2bf(Wcheb[(size_t)k * C1_DIM + n]);
        return;
    }
    id -= PREP_B;
    if (id < PREP_C) {
        int n = id % C2_DIM, k = id / C2_DIM;
        Wg1_t[(size_t)n * C1_DIM + k] = f2bf(Wg1[(size_t)k * C2_DIM + n]);
        return;
    }
    id -= PREP_C;
    if (id < PREP_D) {
        int n = id % C3_DIM, k = id / C3_DIM;
        Wg2_t[(size_t)n * C2_DIM + k] = f2bf(Wg2[(size_t)k * C3_DIM + n]);
        return;
    }
    id -= PREP_D;
    // gptr from sorted batch
    int i = id;
    int b = batch[i];
    if (i == 0) { for (int g = 0; g <= b; g++) gptr[g] = 0; }
    else {
        int bp = batch[i - 1];
        for (int g = bp + 1; g <= b; g++) gptr[g] = i;
    }
    if (i == N_NODES - 1) { for (int g = b + 1; g <= N_GRAPHS; g++) gptr[g] = N_NODES; }
}

// ---------- Cheb gather over tcat slices (row stride TC), 4x edge-unrolled ----------
// out_slice = alpha * prop(prev_slice) + beta * base_slice
__global__ __launch_bounds__(256) void gather_cheb_bf(
        const unsigned short* __restrict__ tb,     // tcat + (k-1)*F_IN
        const int* __restrict__ rowptr, const int* __restrict__ col,
        const float* __restrict__ ew,
        const unsigned short* __restrict__ base,   // tcat + (k-2)*F_IN or null
        float alpha, float beta,
        unsigned short* __restrict__ outc,         // tcat + k*F_IN
        int n) {
    int w = (blockIdx.x * blockDim.x + threadIdx.x) >> 6;
    int lane = threadIdx.x & 63;
    if (w >= n) return;
    float a0 = 0.0f, a1 = 0.0f;
    int rs = rowptr[w], re = rowptr[w + 1];
    for (int b = rs; b < re; b += 64) {
        int cl = 0; float wl = 0.0f;
        if (b + lane < re) { cl = col[b + lane]; wl = ew[b + lane]; }
        int nk4 = (min(64, re - b) + 3) & ~3;   // pad: inactive lanes hold cl=0, wl=0
        for (int j = 0; j < nk4; j += 4) {
            int s0 = __shfl(cl, j), s1 = __shfl(cl, j + 1);
            int s2 = __shfl(cl, j + 2), s3 = __shfl(cl, j + 3);
            float w0 = __shfl(wl, j), w1 = __shfl(wl, j + 1);
            float w2 = __shfl(wl, j + 2), w3 = __shfl(wl, j + 3);
            unsigned u0 = ((const unsigned*)(tb + (size_t)s0 * TC))[lane];
            unsigned u1 = ((const unsigned*)(tb + (size_t)s1 * TC))[lane];
            unsigned u2 = ((const unsigned*)(tb + (size_t)s2 * TC))[lane];
            unsigned u3 = ((const unsigned*)(tb + (size_t)s3 * TC))[lane];
            a0 += w0 * bf_lo(u0) + w1 * bf_lo(u1) + w2 * bf_lo(u2) + w3 * bf_lo(u3);
            a1 += w0 * bf_hi(u0) + w1 * bf_hi(u1) + w2 * bf_hi(u2) + w3 * bf_hi(u3);
        }
    }
    if (base) {
        unsigned ub = ((const unsigned*)(base + (size_t)w * TC))[lane];
        a0 = alpha * a0 + beta * bf_lo(ub);
        a1 = alpha * a1 + beta * bf_hi(ub);
    } else {
        a0 *= alpha; a1 *= alpha;
    }
    ushort2 o; o.x = f2bf(a0); o.y = f2bf(a1);
    *(ushort2*)(outc + (size_t)w * TC + lane * 2) = o;
}

// ---------- GCN pre-aggregation (bf16 in/out), 4x edge-unrolled ----------
template<int FPL>   // C = FPL*64, FPL in {2,4}
__global__ __launch_bounds__(256) void gather_gcn_pre(
        const unsigned short* __restrict__ tb, const int* __restrict__ rowptr,
        const int* __restrict__ col, const float* __restrict__ ew,
        const float* __restrict__ dinv, unsigned short* __restrict__ z, int n) {
    const int C = FPL * 64;
    int w = (blockIdx.x * blockDim.x + threadIdx.x) >> 6;
    int lane = threadIdx.x & 63;
    if (w >= n) return;
    float acc[FPL];
    #pragma unroll
    for (int q = 0; q < FPL; q++) acc[q] = 0.0f;
    int rs = rowptr[w], re = rowptr[w + 1];
    for (int b = rs; b < re; b += 64) {
        int cl = 0; float wl = 0.0f;
        if (b + lane < re) { cl = col[b + lane]; wl = ew[b + lane]; }
        int nk4 = (min(64, re - b) + 3) & ~3;
        for (int j = 0; j < nk4; j += 4) {
            int s0 = __shfl(cl, j), s1 = __shfl(cl, j + 1);
            int s2 = __shfl(cl, j + 2), s3 = __shfl(cl, j + 3);
            float w0 = __shfl(wl, j), w1 = __shfl(wl, j + 1);
            float w2 = __shfl(wl, j + 2), w3 = __shfl(wl, j + 3);
            if constexpr (FPL == 2) {
                unsigned u0 = ((const unsigned*)(tb + (size_t)s0 * C))[lane];
                unsigned u1 = ((const unsigned*)(tb + (size_t)s1 * C))[lane];
                unsigned u2 = ((const unsigned*)(tb + (size_t)s2 * C))[lane];
                unsigned u3 = ((const unsigned*)(tb + (size_t)s3 * C))[lane];
                acc[0] += w0 * bf_lo(u0) + w1 * bf_lo(u1) + w2 * bf_lo(u2) + w3 * bf_lo(u3);
                acc[1] += w0 * bf_hi(u0) + w1 * bf_hi(u1) + w2 * bf_hi(u2) + w3 * bf_hi(u3);
            } else {
                uint2 u0 = ((const uint2*)(tb + (size_t)s0 * C))[lane];
                uint2 u1 = ((const uint2*)(tb + (size_t)s1 * C))[lane];
                uint2 u2 = ((const uint2*)(tb + (size_t)s2 * C))[lane];
                uint2 u3 = ((const uint2*)(tb + (size_t)s3 * C))[lane];
                acc[0] += w0 * bf_lo(u0.x) + w1 * bf_lo(u1.x) + w2 * bf_lo(u2.x) + w3 * bf_lo(u3.x);
                acc[1] += w0 * bf_hi(u0.x) + w1 * bf_hi(u1.x) + w2 * bf_hi(u2.x) + w3 * bf_hi(u3.x);
                acc[2] += w0 * bf_lo(u0.y) + w1 * bf_lo(u1.y) + w2 * bf_lo(u2.y) + w3 * bf_lo(u3.y);
                acc[3] += w0 * bf_hi(u0.y) + w1 * bf_hi(u1.y) + w2 * bf_hi(u2.y) + w3 * bf_hi(u3.y);
            }
        }
    }
    float sn = dinv[w] * dinv[w];
    if constexpr (FPL == 2) {
        unsigned u = ((const unsigned*)(tb + (size_t)w * C))[lane];
        acc[0] += sn * bf_lo(u); acc[1] += sn * bf_hi(u);
        ushort2 o; o.x = f2bf(acc[0]); o.y = f2bf(acc[1]);
        *(ushort2*)(z + (size_t)w * C + lane * 2) = o;
    } else {
        uint2 u = ((const uint2*)(tb + (size_t)w * C))[lane];
        acc[0] += sn * bf_lo(u.x); acc[1] += sn * bf_hi(u.x);
        acc[2] += sn * bf_lo(u.y); acc[3] += sn * bf_hi(u.y);
        ushort4 o; o.x = f2bf(acc[0]); o.y = f2bf(acc[1]);
        o.z = f2bf(acc[2]); o.w = f2bf(acc[3]);
        *(ushort4*)(z + (size_t)w * C + lane * 4) = o;
    }
}

// ---------- bf16 MFMA GEMM: C[M,N] = relu(A[M,K] @ Bt[N,K]^T + bias) ----------
// 64x128 block tile, 4 waves (2 row-halves x 2 col-halves), wave = 32x64 = 2x4 MFMA 16x16x32.
// strideA: A row stride in elements (lets A be a tcat-like strided view).
__global__ __launch_bounds__(256) void gemm_bf16(
        const unsigned short* __restrict__ A, const unsigned short* __restrict__ Bt,
        const float* __restrict__ bias, float* __restrict__ Cf,
        unsigned short* __restrict__ Cb, int M, int K, int N, int relu) {
    int m0 = blockIdx.y * 64, n0 = blockIdx.x * 128;
    int wave = threadIdx.x >> 6, lane = threadIdx.x & 63;
    int wm = (wave & 1) * 32, wn = (wave >> 1) * 64;
    int l15 = lane & 15, quad = lane >> 4;

    v4f acc[2][4];
    #pragma unroll
    for (int i = 0; i < 2; i++)
        #pragma unroll
        for (int j = 0; j < 4; j++) acc[i][j] = (v4f){0.f, 0.f, 0.f, 0.f};

    const unsigned short* Ab[2]; bool av[2];
    #pragma unroll
    for (int i = 0; i < 2; i++) {
        int row = m0 + wm + i * 16 + l15;
        av[i] = row < M;
        Ab[i] = A + (size_t)(av[i] ? row : 0) * K + quad * 8;
    }
    const unsigned short* Bb[4];
    #pragma unroll
    for (int j = 0; j < 4; j++) {
        int coln = n0 + wn + j * 16 + l15;
        Bb[j] = Bt + (size_t)coln * K + quad * 8;
    }
    const v8s zero8 = {0, 0, 0, 0, 0, 0, 0, 0};

    for (int k0 = 0; k0 < K; k0 += 32) {
        v8s a[2], b[4];
        #pragma unroll
        for (int i = 0; i < 2; i++) a[i] = av[i] ? *(const v8s*)(Ab[i] + k0) : zero8;
        #pragma unroll
        for (int j = 0; j < 4; j++) b[j] = *(const v8s*)(Bb[j] + k0);
        #pragma unroll
        for (int i = 0; i < 2; i++)
            #pragma unroll
            for (int j = 0; j < 4; j++)
                acc[i][j] = __builtin_amdgcn_mfma_f32_16x16x32_bf16(a[i], b[j], acc[i][j], 0, 0, 0);
    }

    #pragma unroll
    for (int j = 0; j < 4; j++) {
        int coln = n0 + wn + j * 16 + l15;
        float bv = bias ? bias[coln] : 0.0f;
        #pragma unroll
        for (int i = 0; i < 2; i++) {
            int rbase = m0 + wm + i * 16 + quad * 4;
            #pragma unroll
            for (int r = 0; r < 4; r++) {
                int row = rbase + r;
                if (row >= M) continue;
                float v = acc[i][j][r] + bv;
                if (relu) v = fmaxf(v, 0.0f);
                if (Cf) Cf[(size_t)row * N + coln] = v;
                else    Cb[(size_t)row * N + coln] = f2bf(v);
            }
        }
    }
}

// ---------- gate ----------
__global__ void gate_kernel(const float* __restrict__ h3, const float* __restrict__ wg,
                            const float* __restrict__ bg, float* __restrict__ logits, int n) {
    int node = blockIdx.x * 4 + (threadIdx.x >> 6);
    int lane = threadIdx.x & 63;
    if (node >= n) return;
    float s = 0.0f;
    #pragma unroll
    for (int i = 0; i < 8; i++) {
        int c = i * 64 + lane;
        s += h3[(size_t)node * C3_DIM + c] * wg[c];
    }
    #pragma unroll
    for (int off = 32; off > 0; off >>= 1) s += __shfl_down(s, off);
    if (lane == 0) logits[node] = s + bg[0];
}

// ---------- pool phase A: per-graph softmax stats -> alpha; also zero pooled ----------
__global__ __launch_bounds__(256) void pool_stats(float* __restrict__ logits,
                                                  const int* __restrict__ gptr,
                                                  float* __restrict__ pooled) {
    __shared__ float red[256];
    int g = blockIdx.x, tid = threadIdx.x;
    int gs = gptr[g], ge = gptr[g + 1];
    // zero this graph's pooled row (C3 = 512 floats, 2 per thread)
    pooled[(size_t)g * C3_DIM + tid] = 0.0f;
    pooled[(size_t)g * C3_DIM + 256 + tid] = 0.0f;
    float m = -INFINITY;
    for (int i = gs + tid; i < ge; i += 256) m = fmaxf(m, logits[i]);
    red[tid] = m; __syncthreads();
    for (int off = 128; off > 0; off >>= 1) {
        if (tid < off) red[tid] = fmaxf(red[tid], red[tid + off]);
        __syncthreads();
    }
    m = red[0]; __syncthreads();
    float s = 0.0f;
    for (int i = gs + tid; i < ge; i += 256) s += expf(logits[i] - m);
    red[tid] = s; __syncthreads();
    for (int off = 128; off > 0; off >>= 1) {
        if (tid < off) red[tid] += red[tid + off];
        __syncthreads();
    }
    s = red[0];
    float sinv = (s > 0.0f) ? 1.0f / s : 0.0f;
    for (int i = gs + tid; i < ge; i += 256)
        logits[i] = expf(logits[i] - m) * sinv;   // alpha
}

// ---------- pool phase B: grid (G, C3/256, 8 slices), atomicAdd partials ----------
__global__ __launch_bounds__(256) void pool_partial(const float* __restrict__ h3,
        const float* __restrict__ alpha, const int* __restrict__ gptr,
        float* __restrict__ pooled) {
    int g = blockIdx.x, ch = blockIdx.y, sl = blockIdx.z;
    int gs = gptr[g], ge = gptr[g + 1];
    int cnt = ge - gs;
    int i0 = gs + (cnt * sl) / 8;
    int i1 = gs + (cnt * (sl + 1)) / 8;
    int c = ch * 256 + threadIdx.x;
    float acc = 0.0f;
    for (int i = i0; i < i1; i++)
        acc += alpha[i] * h3[(size_t)i * C3_DIM + c];
    if (i1 > i0) atomicAdd(&pooled[(size_t)g * C3_DIM + c], acc);
}

// ---------- FC + log_softmax ----------
__global__ void fc_kernel(const float* __restrict__ pooled, const float* __restrict__ Wfc,
                          const float* __restrict__ bfc, float* __restrict__ out) {
    int g = blockIdx.x;
    int t = threadIdx.x;
    float acc = -INFINITY;
    if (t < NCLS) {
        acc = bfc[t];
        for (int k = 0; k < C3_DIM; k++)
            acc += pooled[(size_t)g * C3_DIM + k] * Wfc[k * NCLS + t];
    }
    float m = acc;
    #pragma unroll
    for (int off = 8; off > 0; off >>= 1) m = fmaxf(m, __shfl_xor(m, off, 16));
    float e = (t < NCLS) ? expf(acc - m) : 0.0f;
    float s = e;
    #pragma unroll
    for (int off = 8; off > 0; off >>= 1) s += __shfl_xor(s, off, 16);
    if (t < NCLS) out[g * NCLS + t] = acc - m - logf(s);
}

// ---------- host ----------
extern "C" void kernel_launch(void* const* d_in, const int* in_sizes, int n_in,
                              void* d_out, int out_size, void* d_ws, size_t ws_size,
                              hipStream_t stream) {
    const float* x      = (const float*)d_in[0];
    const int*   ei     = (const int*)d_in[1];
    const int*   batch  = (const int*)d_in[2];
    const float* W_cheb = (const float*)d_in[3];
    const float* b_cheb = (const float*)d_in[4];
    const float* W_g1   = (const float*)d_in[5];
    const float* b_g1   = (const float*)d_in[6];
    const float* W_g2   = (const float*)d_in[7];
    const float* b_g2   = (const float*)d_in[8];
    const float* w_gate = (const float*)d_in[9];
    const float* b_gate = (const float*)d_in[10];
    const float* W_fc   = (const float*)d_in[11];
    const float* b_fc   = (const float*)d_in[12];
    const int* src = ei;
    const int* dst = ei + N_EDGES;
    float* out = (float*)d_out;

    const int N = N_NODES, E = N_EDGES, G = N_GRAPHS;

    char* Wp = (char*)d_ws;
    auto alloc = [&](size_t bytes) {
        void* p = Wp;
        Wp += (bytes + 255) & ~(size_t)255;
        return p;
    };
    int*   cnt3    = (int*)alloc((size_t)3 * N * 4);   // cnt_s | cnt_d | fillc (one memset)
    int*   cnt_s   = cnt3;
    int*   cnt_d   = cnt3 + N;
    int*   fillc   = cnt3 + 2 * N;
    int*   rowptr  = (int*)alloc((N + 1) * 4);
    int*   col     = (int*)alloc(E * 4);
    float* wch     = (float*)alloc(E * 4);
    float* nrm     = (float*)alloc(E * 4);
    float* dinv_c  = (float*)alloc(N * 4);
    float* dinv_g  = (float*)alloc(N * 4);
    unsigned short* tcat  = (unsigned short*)alloc((size_t)N * TC * 2);
    unsigned short* h1b   = (unsigned short*)alloc((size_t)N * C1_DIM * 2);
    unsigned short* z1b   = (unsigned short*)alloc((size_t)N * C1_DIM * 2);
    unsigned short* h2b   = (unsigned short*)alloc((size_t)N * C2_DIM * 2);
    unsigned short* z2b   = (unsigned short*)alloc((size_t)N * C2_DIM * 2);
    float* h3      = (float*)alloc((size_t)N * C3_DIM * 4);
    unsigned short* Wcb_t = (unsigned short*)alloc((size_t)TC * C1_DIM * 2);
    unsigned short* Wg1_t = (unsigned short*)alloc((size_t)C1_DIM * C2_DIM * 2);
    unsigned short* Wg2_t = (unsigned short*)alloc((size_t)C2_DIM * C3_DIM * 2);
    float* logits  = (float*)alloc(N * 4);
    int*   gptr    = (int*)alloc((G + 1) * 4);
    float* pooled  = (float*)alloc((size_t)G * C3_DIM * 4);

    dim3 blk(256);
    auto cdiv = [](int a, int b) { return (a + b - 1) / b; };

    // --- prep (independent of CSR): converts + gptr ---
    hipLaunchKernelGGL(prep_kernel, dim3(cdiv(PREP_TOTAL, 256)), blk, 0, stream,
                       x, tcat, W_cheb, Wcb_t, W_g1, Wg1_t, W_g2, Wg2_t, batch, gptr);

    // --- CSR build (dst-sorted) ---
    hipMemsetAsync(cnt3, 0, (size_t)3 * N * sizeof(int), stream);
    hipLaunchKernelGGL(count_kernel, dim3(cdiv(E, 256)), blk, 0, stream, src, dst, cnt_s, cnt_d, E);
    hipLaunchKernelGGL(scan_dinv_kernel, dim3(1), blk, 0, stream, cnt_s, cnt_d, rowptr, dinv_c, dinv_g, N);
    hipLaunchKernelGGL(fill_kernel, dim3(cdiv(E, 256)), blk, 0, stream,
                       src, dst, dinv_c, dinv_g, rowptr, fillc, col, wch, nrm, E);

    const int NWB = cdiv(N, 4);   // gathers: 4 waves/block, 1 node/wave

    // --- Cheb recurrence in bf16 directly on tcat slices ---
    hipLaunchKernelGGL(gather_cheb_bf, dim3(NWB), blk, 0, stream,           // T1 = prop(T0)
                       tcat + 0 * F_IN, rowptr, col, wch,
                       (const unsigned short*)nullptr, 1.0f, 0.0f, tcat + 1 * F_IN, N);
    hipLaunchKernelGGL(gather_cheb_bf, dim3(NWB), blk, 0, stream,           // T2 = 2 prop(T1) - T0
                       tcat + 1 * F_IN, rowptr, col, wch,
                       tcat + 0 * F_IN, 2.0f, -1.0f, tcat + 2 * F_IN, N);
    hipLaunchKernelGGL(gather_cheb_bf, dim3(NWB), blk, 0, stream,           // T3
                       tcat + 2 * F_IN, rowptr, col, wch,
                       tcat + 1 * F_IN, 2.0f, -1.0f, tcat + 3 * F_IN, N);
    hipLaunchKernelGGL(gather_cheb_bf, dim3(NWB), blk, 0, stream,           // T4
                       tcat + 3 * F_IN, rowptr, col, wch,
                       tcat + 2 * F_IN, 2.0f, -1.0f, tcat + 4 * F_IN, N);

    // --- GEMM1: h1 = relu(Tcat @ Wcheb + b_cheb)  [10000,640]x[640,128] ---
    hipLaunchKernelGGL(gemm_bf16, dim3(C1_DIM / 128, cdiv(N, 64)), blk, 0, stream,
                       tcat, Wcb_t, b_cheb, (float*)nullptr, h1b, N, TC, C1_DIM, 1);

    // --- GCN1: pre-aggregate in C1 space, then GEMM ---
    hipLaunchKernelGGL(gather_gcn_pre<2>, dim3(NWB), blk, 0, stream,
                       h1b, rowptr, col, nrm, dinv_g, z1b, N);
    hipLaunchKernelGGL(gemm_bf16, dim3(C2_DIM / 128, cdiv(N, 64)), blk, 0, stream,
                       z1b, Wg1_t, b_g1, (float*)nullptr, h2b, N, C1_DIM, C2_DIM, 1);

    // --- GCN2 ---
    hipLaunchKernelGGL(gather_gcn_pre<4>, dim3(NWB), blk, 0, stream,
                       h2b, rowptr, col, nrm, dinv_g, z2b, N);
    hipLaunchKernelGGL(gemm_bf16, dim3(C3_DIM / 128, cdiv(N, 64)), blk, 0, stream,
                       z2b, Wg2_t, b_g2, h3, (unsigned short*)nullptr, N, C2_DIM, C3_DIM, 1);

    // --- attention pool ---
    hipLaunchKernelGGL(gate_kernel, dim3(cdiv(N, 4)), blk, 0, stream, h3, w_gate, b_gate, logits, N);
    hipLaunchKernelGGL(pool_stats, dim3(G), blk, 0, stream, logits, gptr, pooled);
    hipLaunchKernelGGL(pool_partial, dim3(G, C3_DIM / 256, 8), blk, 0, stream,
                       h3, logits, gptr, pooled);

    // --- FC + log_softmax ---
    hipLaunchKernelGGL(fc_kernel, dim3(G), dim3(64), 0, stream, pooled, W_fc, b_fc, out);
}

// Round 7
// 265.393 us; speedup vs baseline: 11.8967x; 1.1779x over previous
//
#include <hip/hip_runtime.h>
#include <hip/hip_bf16.h>
#include <math.h>

#define N_NODES 10000
#define N_EDGES 160000
#define N_GRAPHS 64
#define F_IN    128
#define C1_DIM  128
#define C2_DIM  256
#define C3_DIM  512
#define K_CHEB  5
#define NCLS    10
#define TC      (K_CHEB * F_IN)    // 640

typedef short v8s __attribute__((ext_vector_type(8)));
typedef float v4f __attribute__((ext_vector_type(4)));

// ---------- bf16 helpers ----------
static __device__ __forceinline__ unsigned short f2bf(float f) {
    unsigned u = __float_as_uint(f);
    unsigned r = (u + 0x7FFFu + ((u >> 16) & 1u)) >> 16;   // RNE
    return (unsigned short)r;
}
static __device__ __forceinline__ float bf_lo(unsigned u) { return __uint_as_float(u << 16); }
static __device__ __forceinline__ float bf_hi(unsigned u) { return __uint_as_float(u & 0xFFFF0000u); }

// ---------- fused prep: x->tcat slice0 | weight transposes | gptr | zero logits | degree count ----------
#define PREP_A (N_NODES * 64)            // x conv, 2 floats per item
#define PREP_B (TC * C1_DIM)             // W_cheb [640,128] -> [128,640]
#define PREP_C (C1_DIM * C2_DIM)         // W_g1
#define PREP_D (C2_DIM * C3_DIM)         // W_g2
#define PREP_E N_NODES                   // gptr
#define PREP_F N_NODES                   // zero logits
#define PREP_G N_EDGES                   // degree count
#define PREP_TOTAL (PREP_A + PREP_B + PREP_C + PREP_D + PREP_E + PREP_F + PREP_G)
__global__ void prep_kernel(const float* __restrict__ x, unsigned short* __restrict__ tcat,
                            const float* __restrict__ Wcheb, unsigned short* __restrict__ Wcb_t,
                            const float* __restrict__ Wg1, unsigned short* __restrict__ Wg1_t,
                            const float* __restrict__ Wg2, unsigned short* __restrict__ Wg2_t,
                            const int* __restrict__ batch, int* __restrict__ gptr,
                            float* __restrict__ logits,
                            const int* __restrict__ src, const int* __restrict__ dst,
                            int* __restrict__ cnt_s, int* __restrict__ cnt_d) {
    int id = blockIdx.x * blockDim.x + threadIdx.x;
    if (id < PREP_A) {
        int n = id >> 6, f = (id & 63) * 2;
        float2 v = *(const float2*)(x + (size_t)n * F_IN + f);
        ushort2 o; o.x = f2bf(v.x); o.y = f2bf(v.y);
        *(ushort2*)(tcat + (size_t)n * TC + f) = o;
        return;
    }
    id -= PREP_A;
    if (id < PREP_B) {
        int n = id % C1_DIM, k = id / C1_DIM;
        Wcb_t[(size_t)n * TC + k] = f2bf(Wcheb[(size_t)k * C1_DIM + n]);
        return;
    }
    id -= PREP_B;
    if (id < PREP_C) {
        int n = id % C2_DIM, k = id / C2_DIM;
        Wg1_t[(size_t)n * C1_DIM + k] = f2bf(Wg1[(size_t)k * C2_DIM + n]);
        return;
    }
    id -= PREP_C;
    if (id < PREP_D) {
        int n = id % C3_DIM, k = id / C3_DIM;
        Wg2_t[(size_t)n * C2_DIM + k] = f2bf(Wg2[(size_t)k * C3_DIM + n]);
        return;
    }
    id -= PREP_D;
    if (id < PREP_E) {
        int i = id;
        int b = batch[i];
        if (i == 0) { for (int g = 0; g <= b; g++) gptr[g] = 0; }
        else {
            int bp = batch[i - 1];
            for (int g = bp + 1; g <= b; g++) gptr[g] = i;
        }
        if (i == N_NODES - 1) { for (int g = b + 1; g <= N_GRAPHS; g++) gptr[g] = N_NODES; }
        return;
    }
    id -= PREP_E;
    if (id < PREP_F) { logits[id] = 0.0f; return; }
    id -= PREP_F;
    if (id < PREP_G) {   // guard the tail! (R6 crash: unguarded fall-through -> wild atomic)
        atomicAdd(&cnt_s[src[id]], 1);
        atomicAdd(&cnt_d[dst[id]], 1);
    }
}

// ---------- CSR: scan (LDS-staged, coalesced) ----------
__global__ __launch_bounds__(256) void scan_kernel(const int* __restrict__ cnt_d,
                                                   int* __restrict__ rowptr, int n) {
    __shared__ int ldsc[N_NODES];
    __shared__ int sums[256];
    int tid = threadIdx.x;
    for (int i = tid; i < n; i += 256) ldsc[i] = cnt_d[i];
    __syncthreads();
    int chunk = (n + 255) / 256;
    int s0 = tid * chunk, s1 = min(n, s0 + chunk);
    if (s0 > n) s0 = n;
    int loc = 0;
    for (int i = s0; i < s1; i++) loc += ldsc[i];
    sums[tid] = loc;
    __syncthreads();
    for (int off = 1; off < 256; off <<= 1) {
        int t = (tid >= off) ? sums[tid - off] : 0;
        __syncthreads();
        sums[tid] += t;
        __syncthreads();
    }
    int pre = sums[tid] - loc;
    for (int i = s0; i < s1; i++) { int v = ldsc[i]; ldsc[i] = pre; pre += v; }
    __syncthreads();
    for (int i = tid; i < n; i += 256) rowptr[i] = ldsc[i];
    if (tid == 255) rowptr[n] = pre;
}

// ---------- CSR: fill (weights computed on the fly from counts) ----------
__global__ void fill_kernel(const int* __restrict__ src, const int* __restrict__ dst,
                            const int* __restrict__ cnt_s, const int* __restrict__ cnt_d,
                            const int* __restrict__ rowptr, int* __restrict__ fillc,
                            int* __restrict__ col, float* __restrict__ wch,
                            float* __restrict__ nrm, int E) {
    int e = blockIdx.x * blockDim.x + threadIdx.x;
    if (e >= E) return;
    int s = src[e], d = dst[e];
    int pos = rowptr[d] + atomicAdd(&fillc[d], 1);
    col[pos] = s;
    int cs = cnt_s[s], cd = cnt_s[d];
    float ds = (cs > 0) ? rsqrtf((float)cs) : 0.0f;
    float dd = (cd > 0) ? rsqrtf((float)cd) : 0.0f;
    wch[pos] = -(ds * dd);
    nrm[pos] = rsqrtf((float)cnt_d[s] + 1.0f) * rsqrtf((float)cnt_d[d] + 1.0f);
}

// ---------- Cheb gather over tcat slices (row stride TC), 8x edge-unrolled ----------
__global__ __launch_bounds__(256) void gather_cheb_bf(
        const unsigned short* __restrict__ tb, const int* __restrict__ rowptr,
        const int* __restrict__ col, const float* __restrict__ ew,
        const unsigned short* __restrict__ base, float alpha, float beta,
        unsigned short* __restrict__ outc, int n) {
    int w = (blockIdx.x * blockDim.x + threadIdx.x) >> 6;
    int lane = threadIdx.x & 63;
    if (w >= n) return;
    float a0 = 0.0f, a1 = 0.0f;
    int rs = rowptr[w], re = rowptr[w + 1];
    for (int b = rs; b < re; b += 64) {
        int cl = 0; float wl = 0.0f;
        if (b + lane < re) { cl = col[b + lane]; wl = ew[b + lane]; }
        int nk8 = (min(64, re - b) + 7) & ~7;   // pad lanes hold cl=0, wl=0
        for (int j = 0; j < nk8; j += 8) {
            int ss[8]; float ww[8]; unsigned uu[8];
            #pragma unroll
            for (int q = 0; q < 8; q++) { ss[q] = __shfl(cl, j + q); ww[q] = __shfl(wl, j + q); }
            #pragma unroll
            for (int q = 0; q < 8; q++) uu[q] = ((const unsigned*)(tb + (size_t)ss[q] * TC))[lane];
            #pragma unroll
            for (int q = 0; q < 8; q++) { a0 += ww[q] * bf_lo(uu[q]); a1 += ww[q] * bf_hi(uu[q]); }
        }
    }
    if (base) {
        unsigned ub = ((const unsigned*)(base + (size_t)w * TC))[lane];
        a0 = alpha * a0 + beta * bf_lo(ub);
        a1 = alpha * a1 + beta * bf_hi(ub);
    } else {
        a0 *= alpha; a1 *= alpha;
    }
    ushort2 o; o.x = f2bf(a0); o.y = f2bf(a1);
    *(ushort2*)(outc + (size_t)w * TC + lane * 2) = o;
}

// ---------- GCN pre-aggregation (bf16 in/out), 8x edge-unrolled ----------
template<int FPL>   // C = FPL*64, FPL in {2,4}
__global__ __launch_bounds__(256) void gather_gcn_pre(
        const unsigned short* __restrict__ tb, const int* __restrict__ rowptr,
        const int* __restrict__ col, const float* __restrict__ ew,
        const int* __restrict__ cnt_d, unsigned short* __restrict__ z, int n) {
    const int C = FPL * 64;
    int w = (blockIdx.x * blockDim.x + threadIdx.x) >> 6;
    int lane = threadIdx.x & 63;
    if (w >= n) return;
    float acc[FPL];
    #pragma unroll
    for (int q = 0; q < FPL; q++) acc[q] = 0.0f;
    int rs = rowptr[w], re = rowptr[w + 1];
    for (int b = rs; b < re; b += 64) {
        int cl = 0; float wl = 0.0f;
        if (b + lane < re) { cl = col[b + lane]; wl = ew[b + lane]; }
        int nk8 = (min(64, re - b) + 7) & ~7;
        for (int j = 0; j < nk8; j += 8) {
            int ss[8]; float ww[8];
            #pragma unroll
            for (int q = 0; q < 8; q++) { ss[q] = __shfl(cl, j + q); ww[q] = __shfl(wl, j + q); }
            if constexpr (FPL == 2) {
                unsigned uu[8];
                #pragma unroll
                for (int q = 0; q < 8; q++) uu[q] = ((const unsigned*)(tb + (size_t)ss[q] * C))[lane];
                #pragma unroll
                for (int q = 0; q < 8; q++) {
                    acc[0] += ww[q] * bf_lo(uu[q]);
                    acc[1] += ww[q] * bf_hi(uu[q]);
                }
            } else {
                uint2 uu[8];
                #pragma unroll
                for (int q = 0; q < 8; q++) uu[q] = ((const uint2*)(tb + (size_t)ss[q] * C))[lane];
                #pragma unroll
                for (int q = 0; q < 8; q++) {
                    acc[0] += ww[q] * bf_lo(uu[q].x); acc[1] += ww[q] * bf_hi(uu[q].x);
                    acc[2] += ww[q] * bf_lo(uu[q].y); acc[3] += ww[q] * bf_hi(uu[q].y);
                }
            }
        }
    }
    float sn = 1.0f / (float)(cnt_d[w] + 1);   // dinv^2 self-loop term
    if constexpr (FPL == 2) {
        unsigned u = ((const unsigned*)(tb + (size_t)w * C))[lane];
        acc[0] += sn * bf_lo(u); acc[1] += sn * bf_hi(u);
        ushort2 o; o.x = f2bf(acc[0]); o.y = f2bf(acc[1]);
        *(ushort2*)(z + (size_t)w * C + lane * 2) = o;
    } else {
        uint2 u = ((const uint2*)(tb + (size_t)w * C))[lane];
        acc[0] += sn * bf_lo(u.x); acc[1] += sn * bf_hi(u.x);
        acc[2] += sn * bf_lo(u.y); acc[3] += sn * bf_hi(u.y);
        ushort4 o; o.x = f2bf(acc[0]); o.y = f2bf(acc[1]);
        o.z = f2bf(acc[2]); o.w = f2bf(acc[3]);
        *(ushort4*)(z + (size_t)w * C + lane * 4) = o;
    }
}

// ---------- bf16 MFMA GEMM: C = relu(A @ Bt^T + bias), optional fused gate dot ----------
// Block tile 64 x (JT*32); 4 waves (2x2); wave tile 32 x (JT*16) = 2 x JT MFMA 16x16x32.
// If wg != null: logits[row] += sum_col v * wg[col] (shfl-reduced, 1 atomic per row per wave).
template<int JT>
__global__ __launch_bounds__(256) void gemm_bf16(
        const unsigned short* __restrict__ A, const unsigned short* __restrict__ Bt,
        const float* __restrict__ bias, float* __restrict__ Cf,
        unsigned short* __restrict__ Cb, const float* __restrict__ wg,
        float* __restrict__ logits, int M, int K, int N, int relu) {
    int m0 = blockIdx.y * 64, n0 = blockIdx.x * (JT * 32);
    int wave = threadIdx.x >> 6, lane = threadIdx.x & 63;
    int wm = (wave & 1) * 32, wn = (wave >> 1) * (JT * 16);
    int l15 = lane & 15, quad = lane >> 4;

    v4f acc[2][JT];
    #pragma unroll
    for (int i = 0; i < 2; i++)
        #pragma unroll
        for (int j = 0; j < JT; j++) acc[i][j] = (v4f){0.f, 0.f, 0.f, 0.f};

    const unsigned short* Ab[2]; bool av[2];
    #pragma unroll
    for (int i = 0; i < 2; i++) {
        int row = m0 + wm + i * 16 + l15;
        av[i] = row < M;
        Ab[i] = A + (size_t)(av[i] ? row : 0) * K + quad * 8;
    }
    const unsigned short* Bb[JT];
    #pragma unroll
    for (int j = 0; j < JT; j++) {
        int coln = n0 + wn + j * 16 + l15;
        Bb[j] = Bt + (size_t)coln * K + quad * 8;
    }
    const v8s zero8 = {0, 0, 0, 0, 0, 0, 0, 0};

    for (int k0 = 0; k0 < K; k0 += 32) {
        v8s a[2], b[JT];
        #pragma unroll
        for (int i = 0; i < 2; i++) a[i] = av[i] ? *(const v8s*)(Ab[i] + k0) : zero8;
        #pragma unroll
        for (int j = 0; j < JT; j++) b[j] = *(const v8s*)(Bb[j] + k0);
        #pragma unroll
        for (int i = 0; i < 2; i++)
            #pragma unroll
            for (int j = 0; j < JT; j++)
                acc[i][j] = __builtin_amdgcn_mfma_f32_16x16x32_bf16(a[i], b[j], acc[i][j], 0, 0, 0);
    }

    float bv[JT], wgj[JT];
    #pragma unroll
    for (int j = 0; j < JT; j++) {
        int coln = n0 + wn + j * 16 + l15;
        bv[j] = bias[coln];
        wgj[j] = wg ? wg[coln] : 0.0f;
    }
    #pragma unroll
    for (int i = 0; i < 2; i++) {
        #pragma unroll
        for (int r = 0; r < 4; r++) {
            int row = m0 + wm + i * 16 + quad * 4 + r;
            if (row >= M) continue;
            float gval = 0.0f;
            #pragma unroll
            for (int j = 0; j < JT; j++) {
                int coln = n0 + wn + j * 16 + l15;
                float v = acc[i][j][r] + bv[j];
                if (relu) v = fmaxf(v, 0.0f);
                if (Cf) Cf[(size_t)row * N + coln] = v;
                else    Cb[(size_t)row * N + coln] = f2bf(v);
                gval += v * wgj[j];
            }
            if (wg) {
                #pragma unroll
                for (int off = 1; off < 16; off <<= 1) gval += __shfl_xor(gval, off);
                if (l15 == 0) atomicAdd(&logits[row], gval);
            }
        }
    }
}

// ---------- pool phase A: per-graph softmax stats -> alpha; zero pooled ----------
__global__ __launch_bounds__(256) void pool_stats(float* __restrict__ logits,
                                                  const int* __restrict__ gptr,
                                                  float* __restrict__ pooled) {
    __shared__ float red[256];
    int g = blockIdx.x, tid = threadIdx.x;
    int gs = gptr[g], ge = gptr[g + 1];
    pooled[(size_t)g * C3_DIM + tid] = 0.0f;
    pooled[(size_t)g * C3_DIM + 256 + tid] = 0.0f;
    float m = -INFINITY;
    for (int i = gs + tid; i < ge; i += 256) m = fmaxf(m, logits[i]);
    red[tid] = m; __syncthreads();
    for (int off = 128; off > 0; off >>= 1) {
        if (tid < off) red[tid] = fmaxf(red[tid], red[tid + off]);
        __syncthreads();
    }
    m = red[0]; __syncthreads();
    float s = 0.0f;
    for (int i = gs + tid; i < ge; i += 256) s += expf(logits[i] - m);
    red[tid] = s; __syncthreads();
    for (int off = 128; off > 0; off >>= 1) {
        if (tid < off) red[tid] += red[tid + off];
        __syncthreads();
    }
    s = red[0];
    float sinv = (s > 0.0f) ? 1.0f / s : 0.0f;
    for (int i = gs + tid; i < ge; i += 256)
        logits[i] = expf(logits[i] - m) * sinv;   // alpha
}

// ---------- pool phase B: grid (G, 8 slices); h3 bf16; 2 feats/thread ----------
__global__ __launch_bounds__(256) void pool_partial(const unsigned short* __restrict__ h3b,
        const float* __restrict__ alpha, const int* __restrict__ gptr,
        float* __restrict__ pooled) {
    int g = blockIdx.x, sl = blockIdx.y, tid = threadIdx.x;
    int gs = gptr[g], ge = gptr[g + 1];
    int cnt = ge - gs;
    int i0 = gs + (cnt * sl) / 8;
    int i1 = gs + (cnt * (sl + 1)) / 8;
    float a0 = 0.0f, a1 = 0.0f;
    for (int i = i0; i < i1; i++) {
        float al = alpha[i];
        unsigned u = ((const unsigned*)(h3b + (size_t)i * C3_DIM))[tid];
        a0 += al * bf_lo(u);
        a1 += al * bf_hi(u);
    }
    if (i1 > i0) {
        atomicAdd(&pooled[(size_t)g * C3_DIM + tid * 2 + 0], a0);
        atomicAdd(&pooled[(size_t)g * C3_DIM + tid * 2 + 1], a1);
    }
}

// ---------- FC + log_softmax ----------
__global__ void fc_kernel(const float* __restrict__ pooled, const float* __restrict__ Wfc,
                          const float* __restrict__ bfc, float* __restrict__ out) {
    int g = blockIdx.x;
    int t = threadIdx.x;
    float acc = -INFINITY;
    if (t < NCLS) {
        acc = bfc[t];
        for (int k = 0; k < C3_DIM; k++)
            acc += pooled[(size_t)g * C3_DIM + k] * Wfc[k * NCLS + t];
    }
    float m = acc;
    #pragma unroll
    for (int off = 8; off > 0; off >>= 1) m = fmaxf(m, __shfl_xor(m, off, 16));
    float e = (t < NCLS) ? expf(acc - m) : 0.0f;
    float s = e;
    #pragma unroll
    for (int off = 8; off > 0; off >>= 1) s += __shfl_xor(s, off, 16);
    if (t < NCLS) out[g * NCLS + t] = acc - m - logf(s);
}

// ---------- host ----------
extern "C" void kernel_launch(void* const* d_in, const int* in_sizes, int n_in,
                              void* d_out, int out_size, void* d_ws, size_t ws_size,
                              hipStream_t stream) {
    const float* x      = (const float*)d_in[0];
    const int*   ei     = (const int*)d_in[1];
    const int*   batch  = (const int*)d_in[2];
    const float* W_cheb = (const float*)d_in[3];
    const float* b_cheb = (const float*)d_in[4];
    const float* W_g1   = (const float*)d_in[5];
    const float* b_g1   = (const float*)d_in[6];
    const float* W_g2   = (const float*)d_in[7];
    const float* b_g2   = (const float*)d_in[8];
    const float* w_gate = (const float*)d_in[9];
    const float* W_fc   = (const float*)d_in[11];
    const float* b_fc   = (const float*)d_in[12];
    const int* src = ei;
    const int* dst = ei + N_EDGES;
    float* out = (float*)d_out;

    const int N = N_NODES, E = N_EDGES, G = N_GRAPHS;

    char* Wp = (char*)d_ws;
    auto alloc = [&](size_t bytes) {
        void* p = Wp;
        Wp += (bytes + 255) & ~(size_t)255;
        return p;
    };
    int*   cnt3    = (int*)alloc((size_t)3 * N * 4);   // cnt_s | cnt_d | fillc (one memset)
    int*   cnt_s   = cnt3;
    int*   cnt_d   = cnt3 + N;
    int*   fillc   = cnt3 + 2 * N;
    int*   rowptr  = (int*)alloc((N + 1) * 4);
    int*   col     = (int*)alloc(E * 4);
    float* wch     = (float*)alloc(E * 4);
    float* nrm     = (float*)alloc(E * 4);
    unsigned short* tcat  = (unsigned short*)alloc((size_t)N * TC * 2);
    unsigned short* h1b   = (unsigned short*)alloc((size_t)N * C1_DIM * 2);
    unsigned short* z1b   = (unsigned short*)alloc((size_t)N * C1_DIM * 2);
    unsigned short* h2b   = (unsigned short*)alloc((size_t)N * C2_DIM * 2);
    unsigned short* z2b   = (unsigned short*)alloc((size_t)N * C2_DIM * 2);
    unsigned short* h3b   = (unsigned short*)alloc((size_t)N * C3_DIM * 2);
    unsigned short* Wcb_t = (unsigned short*)alloc((size_t)TC * C1_DIM * 2);
    unsigned short* Wg1_t = (unsigned short*)alloc((size_t)C1_DIM * C2_DIM * 2);
    unsigned short* Wg2_t = (unsigned short*)alloc((size_t)C2_DIM * C3_DIM * 2);
    float* logits  = (float*)alloc(N * 4);
    int*   gptr    = (int*)alloc((G + 1) * 4);
    float* pooled  = (float*)alloc((size_t)G * C3_DIM * 4);

    dim3 blk(256);
    auto cdiv = [](int a, int b) { return (a + b - 1) / b; };

    // --- memset counters, then fused prep (converts | gptr | zero logits | count) ---
    hipMemsetAsync(cnt3, 0, (size_t)3 * N * sizeof(int), stream);
    hipLaunchKernelGGL(prep_kernel, dim3(cdiv(PREP_TOTAL, 256)), blk, 0, stream,
                       x, tcat, W_cheb, Wcb_t, W_g1, Wg1_t, W_g2, Wg2_t,
                       batch, gptr, logits, src, dst, cnt_s, cnt_d);

    // --- CSR scan + fill ---
    hipLaunchKernelGGL(scan_kernel, dim3(1), blk, 0, stream, cnt_d, rowptr, N);
    hipLaunchKernelGGL(fill_kernel, dim3(cdiv(E, 256)), blk, 0, stream,
                       src, dst, cnt_s, cnt_d, rowptr, fillc, col, wch, nrm, E);

    const int NWB = cdiv(N, 4);   // gathers: 4 waves/block, 1 node/wave

    // --- Cheb recurrence in bf16 directly on tcat slices ---
    hipLaunchKernelGGL(gather_cheb_bf, dim3(NWB), blk, 0, stream,           // T1 = prop(T0)
                       tcat + 0 * F_IN, rowptr, col, wch,
                       (const unsigned short*)nullptr, 1.0f, 0.0f, tcat + 1 * F_IN, N);
    hipLaunchKernelGGL(gather_cheb_bf, dim3(NWB), blk, 0, stream,           // T2 = 2 prop(T1) - T0
                       tcat + 1 * F_IN, rowptr, col, wch,
                       tcat + 0 * F_IN, 2.0f, -1.0f, tcat + 2 * F_IN, N);
    hipLaunchKernelGGL(gather_cheb_bf, dim3(NWB), blk, 0, stream,           // T3
                       tcat + 2 * F_IN, rowptr, col, wch,
                       tcat + 1 * F_IN, 2.0f, -1.0f, tcat + 3 * F_IN, N);
    hipLaunchKernelGGL(gather_cheb_bf, dim3(NWB), blk, 0, stream,           // T4
                       tcat + 3 * F_IN, rowptr, col, wch,
                       tcat + 2 * F_IN, 2.0f, -1.0f, tcat + 4 * F_IN, N);

    // --- GEMM1: h1 = relu(Tcat @ Wcheb + b)  [10000,640]x[640,128], 64-col tiles ---
    hipLaunchKernelGGL(gemm_bf16<2>, dim3(C1_DIM / 64, cdiv(N, 64)), blk, 0, stream,
                       tcat, Wcb_t, b_cheb, (float*)nullptr, h1b,
                       (const float*)nullptr, (float*)nullptr, N, TC, C1_DIM, 1);

    // --- GCN1: pre-aggregate in C1 space, then GEMM ---
    hipLaunchKernelGGL(gather_gcn_pre<2>, dim3(NWB), blk, 0, stream,
                       h1b, rowptr, col, nrm, cnt_d, z1b, N);
    hipLaunchKernelGGL(gemm_bf16<4>, dim3(C2_DIM / 128, cdiv(N, 64)), blk, 0, stream,
                       z1b, Wg1_t, b_g1, (float*)nullptr, h2b,
                       (const float*)nullptr, (float*)nullptr, N, C1_DIM, C2_DIM, 1);

    // --- GCN2 + fused gate dot-product (b_gate dropped: softmax shift-invariant) ---
    hipLaunchKernelGGL(gather_gcn_pre<4>, dim3(NWB), blk, 0, stream,
                       h2b, rowptr, col, nrm, cnt_d, z2b, N);
    hipLaunchKernelGGL(gemm_bf16<4>, dim3(C3_DIM / 128, cdiv(N, 64)), blk, 0, stream,
                       z2b, Wg2_t, b_g2, (float*)nullptr, h3b,
                       w_gate, logits, N, C2_DIM, C3_DIM, 1);

    // --- attention pool ---
    hipLaunchKernelGGL(pool_stats, dim3(G), blk, 0, stream, logits, gptr, pooled);
    hipLaunchKernelGGL(pool_partial, dim3(G, 8), blk, 0, stream, h3b, logits, gptr, pooled);

    // --- FC + log_softmax ---
    hipLaunchKernelGGL(fc_kernel, dim3(G), dim3(64), 0, stream, pooled, W_fc, b_fc, out);
}

// Round 8
// 263.801 us; speedup vs baseline: 11.9685x; 1.0060x over previous
//
#include <hip/hip_runtime.h>
#include <hip/hip_bf16.h>
#include <math.h>

#define N_NODES 10000
#define N_EDGES 160000
#define N_GRAPHS 64
#define F_IN    128
#define C1_DIM  128
#define C2_DIM  256
#define C3_DIM  512
#define K_CHEB  5
#define NCLS    10
#define TC      (K_CHEB * F_IN)    // 640

typedef short v8s __attribute__((ext_vector_type(8)));
typedef float v4f __attribute__((ext_vector_type(4)));

// ---------- bf16 helpers ----------
static __device__ __forceinline__ unsigned short f2bf(float f) {
    unsigned u = __float_as_uint(f);
    unsigned r = (u + 0x7FFFu + ((u >> 16) & 1u)) >> 16;   // RNE
    return (unsigned short)r;
}
static __device__ __forceinline__ float bf_lo(unsigned u) { return __uint_as_float(u << 16); }
static __device__ __forceinline__ float bf_hi(unsigned u) { return __uint_as_float(u & 0xFFFF0000u); }

// ---------- fused prep ----------
// sections: x->tcat slice0 | 3 weight transposes (coalesced WRITES) | gptr |
//           zero logits | zero pooled | edge degree count (guarded tail)
#define PREP_A (N_NODES * 64)            // x conv, 2 floats per item
#define PREP_B (TC * C1_DIM)             // W_cheb [640,128] -> [128,640]
#define PREP_C (C1_DIM * C2_DIM)         // W_g1
#define PREP_D (C2_DIM * C3_DIM)         // W_g2
#define PREP_E N_NODES                   // gptr
#define PREP_F N_NODES                   // zero logits
#define PREP_H (N_GRAPHS * C3_DIM)       // zero pooled
#define PREP_G N_EDGES                   // degree count
#define PREP_TOTAL (PREP_A + PREP_B + PREP_C + PREP_D + PREP_E + PREP_F + PREP_H + PREP_G)
__global__ void prep_kernel(const float* __restrict__ x, unsigned short* __restrict__ tcat,
                            const float* __restrict__ Wcheb, unsigned short* __restrict__ Wcb_t,
                            const float* __restrict__ Wg1, unsigned short* __restrict__ Wg1_t,
                            const float* __restrict__ Wg2, unsigned short* __restrict__ Wg2_t,
                            const int* __restrict__ batch, int* __restrict__ gptr,
                            float* __restrict__ logits, float* __restrict__ pooled,
                            const int* __restrict__ src, const int* __restrict__ dst,
                            int* __restrict__ cnt_s, int* __restrict__ cnt_d) {
    int id = blockIdx.x * blockDim.x + threadIdx.x;
    if (id < PREP_A) {
        int n = id >> 6, f = (id & 63) * 2;
        float2 v = *(const float2*)(x + (size_t)n * F_IN + f);
        ushort2 o; o.x = f2bf(v.x); o.y = f2bf(v.y);
        *(ushort2*)(tcat + (size_t)n * TC + f) = o;
        return;
    }
    id -= PREP_A;
    if (id < PREP_B) {           // write-coalesced: consecutive id -> consecutive k
        int k = id % TC, n = id / TC;
        Wcb_t[(size_t)n * TC + k] = f2bf(Wcheb[(size_t)k * C1_DIM + n]);
        return;
    }
    id -= PREP_B;
    if (id < PREP_C) {
        int k = id % C1_DIM, n = id / C1_DIM;
        Wg1_t[(size_t)n * C1_DIM + k] = f2bf(Wg1[(size_t)k * C2_DIM + n]);
        return;
    }
    id -= PREP_C;
    if (id < PREP_D) {
        int k = id % C2_DIM, n = id / C2_DIM;
        Wg2_t[(size_t)n * C2_DIM + k] = f2bf(Wg2[(size_t)k * C3_DIM + n]);
        return;
    }
    id -= PREP_D;
    if (id < PREP_E) {
        int i = id;
        int b = batch[i];
        if (i == 0) { for (int g = 0; g <= b; g++) gptr[g] = 0; }
        else {
            int bp = batch[i - 1];
            for (int g = bp + 1; g <= b; g++) gptr[g] = i;
        }
        if (i == N_NODES - 1) { for (int g = b + 1; g <= N_GRAPHS; g++) gptr[g] = N_NODES; }
        return;
    }
    id -= PREP_E;
    if (id < PREP_F) { logits[id] = 0.0f; return; }
    id -= PREP_F;
    if (id < PREP_H) { pooled[id] = 0.0f; return; }
    id -= PREP_H;
    if (id < PREP_G) {   // guarded tail (R6 lesson)
        atomicAdd(&cnt_s[src[id]], 1);
        atomicAdd(&cnt_d[dst[id]], 1);
    }
}

// ---------- CSR: scan (LDS-staged, coalesced) ----------
__global__ __launch_bounds__(256) void scan_kernel(const int* __restrict__ cnt_d,
                                                   int* __restrict__ rowptr, int n) {
    __shared__ int ldsc[N_NODES];
    __shared__ int sums[256];
    int tid = threadIdx.x;
    for (int i = tid; i < n; i += 256) ldsc[i] = cnt_d[i];
    __syncthreads();
    int chunk = (n + 255) / 256;
    int s0 = tid * chunk, s1 = min(n, s0 + chunk);
    if (s0 > n) s0 = n;
    int loc = 0;
    for (int i = s0; i < s1; i++) loc += ldsc[i];
    sums[tid] = loc;
    __syncthreads();
    for (int off = 1; off < 256; off <<= 1) {
        int t = (tid >= off) ? sums[tid - off] : 0;
        __syncthreads();
        sums[tid] += t;
        __syncthreads();
    }
    int pre = sums[tid] - loc;
    for (int i = s0; i < s1; i++) { int v = ldsc[i]; ldsc[i] = pre; pre += v; }
    __syncthreads();
    for (int i = tid; i < n; i += 256) rowptr[i] = ldsc[i];
    if (tid == 255) rowptr[n] = pre;
}

// ---------- CSR: fill -> packed (col, weight) records ----------
__global__ void fill_kernel(const int* __restrict__ src, const int* __restrict__ dst,
                            const int* __restrict__ cnt_s, const int* __restrict__ cnt_d,
                            const int* __restrict__ rowptr, int* __restrict__ fillc,
                            int2* __restrict__ ecb, int2* __restrict__ egc, int E) {
    int e = blockIdx.x * blockDim.x + threadIdx.x;
    if (e >= E) return;
    int s = src[e], d = dst[e];
    int pos = rowptr[d] + atomicAdd(&fillc[d], 1);
    int cs = cnt_s[s], cd = cnt_s[d];
    float ds = (cs > 0) ? rsqrtf((float)cs) : 0.0f;
    float dd = (cd > 0) ? rsqrtf((float)cd) : 0.0f;
    float nr = rsqrtf((float)cnt_d[s] + 1.0f) * rsqrtf((float)cnt_d[d] + 1.0f);
    ecb[pos] = make_int2(s, __float_as_int(-(ds * dd)));
    egc[pos] = make_int2(s, __float_as_int(nr));
}

// ---------- Cheb gather over tcat slices (row stride TC), 8x edge-unrolled ----------
__global__ __launch_bounds__(256) void gather_cheb_bf(
        const unsigned short* __restrict__ tb, const int* __restrict__ rowptr,
        const int2* __restrict__ edges,
        const unsigned short* __restrict__ base, float alpha, float beta,
        unsigned short* __restrict__ outc, int n) {
    int w = (blockIdx.x * blockDim.x + threadIdx.x) >> 6;
    int lane = threadIdx.x & 63;
    if (w >= n) return;
    float a0 = 0.0f, a1 = 0.0f;
    int rs = rowptr[w], re = rowptr[w + 1];
    for (int b = rs; b < re; b += 64) {
        int cl = 0; float wl = 0.0f;
        if (b + lane < re) { int2 e = edges[b + lane]; cl = e.x; wl = __int_as_float(e.y); }
        int nk8 = (min(64, re - b) + 7) & ~7;   // pad lanes hold cl=0, wl=0
        for (int j = 0; j < nk8; j += 8) {
            int ss[8]; float ww[8]; unsigned uu[8];
            #pragma unroll
            for (int q = 0; q < 8; q++) { ss[q] = __shfl(cl, j + q); ww[q] = __shfl(wl, j + q); }
            #pragma unroll
            for (int q = 0; q < 8; q++) uu[q] = ((const unsigned*)(tb + (size_t)ss[q] * TC))[lane];
            #pragma unroll
            for (int q = 0; q < 8; q++) { a0 += ww[q] * bf_lo(uu[q]); a1 += ww[q] * bf_hi(uu[q]); }
        }
    }
    if (base) {
        unsigned ub = ((const unsigned*)(base + (size_t)w * TC))[lane];
        a0 = alpha * a0 + beta * bf_lo(ub);
        a1 = alpha * a1 + beta * bf_hi(ub);
    } else {
        a0 *= alpha; a1 *= alpha;
    }
    ushort2 o; o.x = f2bf(a0); o.y = f2bf(a1);
    *(ushort2*)(outc + (size_t)w * TC + lane * 2) = o;
}

// ---------- GCN pre-aggregation (bf16 in/out), 8x edge-unrolled ----------
template<int FPL>   // C = FPL*64, FPL in {2,4}
__global__ __launch_bounds__(256) void gather_gcn_pre(
        const unsigned short* __restrict__ tb, const int* __restrict__ rowptr,
        const int2* __restrict__ edges,
        const int* __restrict__ cnt_d, unsigned short* __restrict__ z, int n) {
    const int C = FPL * 64;
    int w = (blockIdx.x * blockDim.x + threadIdx.x) >> 6;
    int lane = threadIdx.x & 63;
    if (w >= n) return;
    float acc[FPL];
    #pragma unroll
    for (int q = 0; q < FPL; q++) acc[q] = 0.0f;
    int rs = rowptr[w], re = rowptr[w + 1];
    for (int b = rs; b < re; b += 64) {
        int cl = 0; float wl = 0.0f;
        if (b + lane < re) { int2 e = edges[b + lane]; cl = e.x; wl = __int_as_float(e.y); }
        int nk8 = (min(64, re - b) + 7) & ~7;
        for (int j = 0; j < nk8; j += 8) {
            int ss[8]; float ww[8];
            #pragma unroll
            for (int q = 0; q < 8; q++) { ss[q] = __shfl(cl, j + q); ww[q] = __shfl(wl, j + q); }
            if constexpr (FPL == 2) {
                unsigned uu[8];
                #pragma unroll
                for (int q = 0; q < 8; q++) uu[q] = ((const unsigned*)(tb + (size_t)ss[q] * C))[lane];
                #pragma unroll
                for (int q = 0; q < 8; q++) {
                    acc[0] += ww[q] * bf_lo(uu[q]);
                    acc[1] += ww[q] * bf_hi(uu[q]);
                }
            } else {
                uint2 uu[8];
                #pragma unroll
                for (int q = 0; q < 8; q++) uu[q] = ((const uint2*)(tb + (size_t)ss[q] * C))[lane];
                #pragma unroll
                for (int q = 0; q < 8; q++) {
                    acc[0] += ww[q] * bf_lo(uu[q].x); acc[1] += ww[q] * bf_hi(uu[q].x);
                    acc[2] += ww[q] * bf_lo(uu[q].y); acc[3] += ww[q] * bf_hi(uu[q].y);
                }
            }
        }
    }
    float sn = 1.0f / (float)(cnt_d[w] + 1);   // dinv^2 self-loop term
    if constexpr (FPL == 2) {
        unsigned u = ((const unsigned*)(tb + (size_t)w * C))[lane];
        acc[0] += sn * bf_lo(u); acc[1] += sn * bf_hi(u);
        ushort2 o; o.x = f2bf(acc[0]); o.y = f2bf(acc[1]);
        *(ushort2*)(z + (size_t)w * C + lane * 2) = o;
    } else {
        uint2 u = ((const uint2*)(tb + (size_t)w * C))[lane];
        acc[0] += sn * bf_lo(u.x); acc[1] += sn * bf_hi(u.x);
        acc[2] += sn * bf_lo(u.y); acc[3] += sn * bf_hi(u.y);
        ushort4 o; o.x = f2bf(acc[0]); o.y = f2bf(acc[1]);
        o.z = f2bf(acc[2]); o.w = f2bf(acc[3]);
        *(ushort4*)(z + (size_t)w * C + lane * 4) = o;
    }
}

// ---------- bf16 MFMA GEMM: C = relu(A @ Bt^T + bias), optional fused gate dot ----------
template<int JT>
__global__ __launch_bounds__(256) void gemm_bf16(
        const unsigned short* __restrict__ A, const unsigned short* __restrict__ Bt,
        const float* __restrict__ bias, float* __restrict__ Cf,
        unsigned short* __restrict__ Cb, const float* __restrict__ wg,
        float* __restrict__ logits, int M, int K, int N, int relu) {
    int m0 = blockIdx.y * 64, n0 = blockIdx.x * (JT * 32);
    int wave = threadIdx.x >> 6, lane = threadIdx.x & 63;
    int wm = (wave & 1) * 32, wn = (wave >> 1) * (JT * 16);
    int l15 = lane & 15, quad = lane >> 4;

    v4f acc[2][JT];
    #pragma unroll
    for (int i = 0; i < 2; i++)
        #pragma unroll
        for (int j = 0; j < JT; j++) acc[i][j] = (v4f){0.f, 0.f, 0.f, 0.f};

    const unsigned short* Ab[2]; bool av[2];
    #pragma unroll
    for (int i = 0; i < 2; i++) {
        int row = m0 + wm + i * 16 + l15;
        av[i] = row < M;
        Ab[i] = A + (size_t)(av[i] ? row : 0) * K + quad * 8;
    }
    const unsigned short* Bb[JT];
    #pragma unroll
    for (int j = 0; j < JT; j++) {
        int coln = n0 + wn + j * 16 + l15;
        Bb[j] = Bt + (size_t)coln * K + quad * 8;
    }
    const v8s zero8 = {0, 0, 0, 0, 0, 0, 0, 0};

    for (int k0 = 0; k0 < K; k0 += 32) {
        v8s a[2], b[JT];
        #pragma unroll
        for (int i = 0; i < 2; i++) a[i] = av[i] ? *(const v8s*)(Ab[i] + k0) : zero8;
        #pragma unroll
        for (int j = 0; j < JT; j++) b[j] = *(const v8s*)(Bb[j] + k0);
        #pragma unroll
        for (int i = 0; i < 2; i++)
            #pragma unroll
            for (int j = 0; j < JT; j++)
                acc[i][j] = __builtin_amdgcn_mfma_f32_16x16x32_bf16(a[i], b[j], acc[i][j], 0, 0, 0);
    }

    float bv[JT], wgj[JT];
    #pragma unroll
    for (int j = 0; j < JT; j++) {
        int coln = n0 + wn + j * 16 + l15;
        bv[j] = bias[coln];
        wgj[j] = wg ? wg[coln] : 0.0f;
    }
    #pragma unroll
    for (int i = 0; i < 2; i++) {
        #pragma unroll
        for (int r = 0; r < 4; r++) {
            int row = m0 + wm + i * 16 + quad * 4 + r;
            if (row >= M) continue;
            float gval = 0.0f;
            #pragma unroll
            for (int j = 0; j < JT; j++) {
                int coln = n0 + wn + j * 16 + l15;
                float v = acc[i][j][r] + bv[j];
                if (relu) v = fmaxf(v, 0.0f);
                if (Cf) Cf[(size_t)row * N + coln] = v;
                else    Cb[(size_t)row * N + coln] = f2bf(v);
                gval += v * wgj[j];
            }
            if (wg) {
                #pragma unroll
                for (int off = 1; off < 16; off <<= 1) gval += __shfl_xor(gval, off);
                if (l15 == 0) atomicAdd(&logits[row], gval);
            }
        }
    }
}

// ---------- fused pool: grid (G, 8 slices); per-block redundant softmax stats ----------
__global__ __launch_bounds__(256) void pool_partial(const unsigned short* __restrict__ h3b,
        const float* __restrict__ logits, const int* __restrict__ gptr,
        float* __restrict__ pooled) {
    __shared__ float red[256];
    int g = blockIdx.x, sl = blockIdx.y, tid = threadIdx.x;
    int gs = gptr[g], ge = gptr[g + 1];
    // stats (redundant per slice-block; ~156 logits, L2-hot)
    float m = -INFINITY;
    for (int i = gs + tid; i < ge; i += 256) m = fmaxf(m, logits[i]);
    red[tid] = m; __syncthreads();
    for (int off = 128; off > 0; off >>= 1) {
        if (tid < off) red[tid] = fmaxf(red[tid], red[tid + off]);
        __syncthreads();
    }
    m = red[0]; __syncthreads();
    float s = 0.0f;
    for (int i = gs + tid; i < ge; i += 256) s += expf(logits[i] - m);
    red[tid] = s; __syncthreads();
    for (int off = 128; off > 0; off >>= 1) {
        if (tid < off) red[tid] += red[tid + off];
        __syncthreads();
    }
    s = red[0];
    float sinv = (s > 0.0f) ? 1.0f / s : 0.0f;
    // weighted feature partial sum over this slice
    int cnt = ge - gs;
    int i0 = gs + (cnt * sl) / 8;
    int i1 = gs + (cnt * (sl + 1)) / 8;
    float a0 = 0.0f, a1 = 0.0f;
    for (int i = i0; i < i1; i++) {
        float al = expf(logits[i] - m) * sinv;
        unsigned u = ((const unsigned*)(h3b + (size_t)i * C3_DIM))[tid];
        a0 += al * bf_lo(u);
        a1 += al * bf_hi(u);
    }
    if (i1 > i0) {
        atomicAdd(&pooled[(size_t)g * C3_DIM + tid * 2 + 0], a0);
        atomicAdd(&pooled[(size_t)g * C3_DIM + tid * 2 + 1], a1);
    }
}

// ---------- FC + log_softmax ----------
__global__ void fc_kernel(const float* __restrict__ pooled, const float* __restrict__ Wfc,
                          const float* __restrict__ bfc, float* __restrict__ out) {
    int g = blockIdx.x;
    int t = threadIdx.x;
    float acc = -INFINITY;
    if (t < NCLS) {
        acc = bfc[t];
        for (int k = 0; k < C3_DIM; k++)
            acc += pooled[(size_t)g * C3_DIM + k] * Wfc[k * NCLS + t];
    }
    float m = acc;
    #pragma unroll
    for (int off = 8; off > 0; off >>= 1) m = fmaxf(m, __shfl_xor(m, off, 16));
    float e = (t < NCLS) ? expf(acc - m) : 0.0f;
    float s = e;
    #pragma unroll
    for (int off = 8; off > 0; off >>= 1) s += __shfl_xor(s, off, 16);
    if (t < NCLS) out[g * NCLS + t] = acc - m - logf(s);
}

// ---------- host ----------
extern "C" void kernel_launch(void* const* d_in, const int* in_sizes, int n_in,
                              void* d_out, int out_size, void* d_ws, size_t ws_size,
                              hipStream_t stream) {
    const float* x      = (const float*)d_in[0];
    const int*   ei     = (const int*)d_in[1];
    const int*   batch  = (const int*)d_in[2];
    const float* W_cheb = (const float*)d_in[3];
    const float* b_cheb = (const float*)d_in[4];
    const float* W_g1   = (const float*)d_in[5];
    const float* b_g1   = (const float*)d_in[6];
    const float* W_g2   = (const float*)d_in[7];
    const float* b_g2   = (const float*)d_in[8];
    const float* w_gate = (const float*)d_in[9];
    const float* W_fc   = (const float*)d_in[11];
    const float* b_fc   = (const float*)d_in[12];
    const int* src = ei;
    const int* dst = ei + N_EDGES;
    float* out = (float*)d_out;

    const int N = N_NODES, E = N_EDGES, G = N_GRAPHS;

    char* Wp = (char*)d_ws;
    auto alloc = [&](size_t bytes) {
        void* p = Wp;
        Wp += (bytes + 255) & ~(size_t)255;
        return p;
    };
    int*   cnt3    = (int*)alloc((size_t)3 * N * 4);   // cnt_s | cnt_d | fillc (one memset)
    int*   cnt_s   = cnt3;
    int*   cnt_d   = cnt3 + N;
    int*   fillc   = cnt3 + 2 * N;
    int*   rowptr  = (int*)alloc((N + 1) * 4);
    int2*  ecb     = (int2*)alloc((size_t)E * 8);      // (col, wch) packed
    int2*  egc     = (int2*)alloc((size_t)E * 8);      // (col, nrm) packed
    unsigned short* tcat  = (unsigned short*)alloc((size_t)N * TC * 2);
    unsigned short* h1b   = (unsigned short*)alloc((size_t)N * C1_DIM * 2);
    unsigned short* z1b   = (unsigned short*)alloc((size_t)N * C1_DIM * 2);
    unsigned short* h2b   = (unsigned short*)alloc((size_t)N * C2_DIM * 2);
    unsigned short* z2b   = (unsigned short*)alloc((size_t)N * C2_DIM * 2);
    unsigned short* h3b   = (unsigned short*)alloc((size_t)N * C3_DIM * 2);
    unsigned short* Wcb_t = (unsigned short*)alloc((size_t)TC * C1_DIM * 2);
    unsigned short* Wg1_t = (unsigned short*)alloc((size_t)C1_DIM * C2_DIM * 2);
    unsigned short* Wg2_t = (unsigned short*)alloc((size_t)C2_DIM * C3_DIM * 2);
    float* logits  = (float*)alloc(N * 4);
    int*   gptr    = (int*)alloc((G + 1) * 4);
    float* pooled  = (float*)alloc((size_t)G * C3_DIM * 4);

    dim3 blk(256);
    auto cdiv = [](int a, int b) { return (a + b - 1) / b; };

    // --- memset counters, fused prep (converts | gptr | zeros | count) ---
    hipMemsetAsync(cnt3, 0, (size_t)3 * N * sizeof(int), stream);
    hipLaunchKernelGGL(prep_kernel, dim3(cdiv(PREP_TOTAL, 256)), blk, 0, stream,
                       x, tcat, W_cheb, Wcb_t, W_g1, Wg1_t, W_g2, Wg2_t,
                       batch, gptr, logits, pooled, src, dst, cnt_s, cnt_d);

    // --- CSR scan + fill ---
    hipLaunchKernelGGL(scan_kernel, dim3(1), blk, 0, stream, cnt_d, rowptr, N);
    hipLaunchKernelGGL(fill_kernel, dim3(cdiv(E, 256)), blk, 0, stream,
                       src, dst, cnt_s, cnt_d, rowptr, fillc, ecb, egc, E);

    const int NWB = cdiv(N, 4);   // gathers: 4 waves/block, 1 node/wave

    // --- Cheb recurrence in bf16 directly on tcat slices ---
    hipLaunchKernelGGL(gather_cheb_bf, dim3(NWB), blk, 0, stream,           // T1 = prop(T0)
                       tcat + 0 * F_IN, rowptr, ecb,
                       (const unsigned short*)nullptr, 1.0f, 0.0f, tcat + 1 * F_IN, N);
    hipLaunchKernelGGL(gather_cheb_bf, dim3(NWB), blk, 0, stream,           // T2 = 2 prop(T1) - T0
                       tcat + 1 * F_IN, rowptr, ecb,
                       tcat + 0 * F_IN, 2.0f, -1.0f, tcat + 2 * F_IN, N);
    hipLaunchKernelGGL(gather_cheb_bf, dim3(NWB), blk, 0, stream,           // T3
                       tcat + 2 * F_IN, rowptr, ecb,
                       tcat + 1 * F_IN, 2.0f, -1.0f, tcat + 3 * F_IN, N);
    hipLaunchKernelGGL(gather_cheb_bf, dim3(NWB), blk, 0, stream,           // T4
                       tcat + 3 * F_IN, rowptr, ecb,
                       tcat + 2 * F_IN, 2.0f, -1.0f, tcat + 4 * F_IN, N);

    // --- GEMM1: h1 = relu(Tcat @ Wcheb + b)  [10000,640]x[640,128] ---
    hipLaunchKernelGGL(gemm_bf16<2>, dim3(C1_DIM / 64, cdiv(N, 64)), blk, 0, stream,
                       tcat, Wcb_t, b_cheb, (float*)nullptr, h1b,
                       (const float*)nullptr, (float*)nullptr, N, TC, C1_DIM, 1);

    // --- GCN1: pre-aggregate in C1 space, then GEMM ---
    hipLaunchKernelGGL(gather_gcn_pre<2>, dim3(NWB), blk, 0, stream,
                       h1b, rowptr, egc, cnt_d, z1b, N);
    hipLaunchKernelGGL(gemm_bf16<4>, dim3(C2_DIM / 128, cdiv(N, 64)), blk, 0, stream,
                       z1b, Wg1_t, b_g1, (float*)nullptr, h2b,
                       (const float*)nullptr, (float*)nullptr, N, C1_DIM, C2_DIM, 1);

    // --- GCN2 + fused gate dot-product ---
    hipLaunchKernelGGL(gather_gcn_pre<4>, dim3(NWB), blk, 0, stream,
                       h2b, rowptr, egc, cnt_d, z2b, N);
    hipLaunchKernelGGL(gemm_bf16<4>, dim3(C3_DIM / 128, cdiv(N, 64)), blk, 0, stream,
                       z2b, Wg2_t, b_g2, (float*)nullptr, h3b,
                       w_gate, logits, N, C2_DIM, C3_DIM, 1);

    // --- fused attention pool (stats inline) + FC ---
    hipLaunchKernelGGL(pool_partial, dim3(G, 8), blk, 0, stream, h3b, logits, gptr, pooled);
    hipLaunchKernelGGL(fc_kernel, dim3(G), dim3(64), 0, stream, pooled, W_fc, b_fc, out);
}